// Round 12
// baseline (356.330 us; speedup 1.0000x reference)
//
#include <hip/hip_runtime.h>
#include <math.h>

#define BB 16
#define SS 16
#define VVV 64
#define EE 64
#define HHH 8
#define NLAYER 4
#define DFF_ 2048
#define LL 1024   /* S*V */
#define BL 16384  /* B*L */
#define PERL 131072  /* 64*2048 elems per layer of W1 (and W2); 32 tiles*4096 */
#define NBLK 512

typedef __attribute__((ext_vector_type(8))) _Float16 half8;
typedef __attribute__((ext_vector_type(4))) _Float16 half4v;
typedef __attribute__((ext_vector_type(2))) _Float16 half2v;
typedef __attribute__((ext_vector_type(4))) float f32x4;

#if defined(__has_builtin)
#if __has_builtin(__builtin_amdgcn_fdot2)
#define HAVE_FDOT2 1
#endif
#endif

#define AGS __HIP_MEMORY_SCOPE_AGENT

// XOR-swizzled index into row-major fp16 LDS tiles with 64-half (128 B) rows.
#define SW64(m, k)  (((m) << 6) + ((((k) >> 3) ^ ((m) & 7)) << 3) + ((k) & 7))

// ---- one-shot grid barriers (bar blocks zeroed by k_prep each launch) ----
// Plain: relaxed-only (used as phase-2 of the coherent fallback).
__device__ __forceinline__ void gsync_plain(unsigned int* B, int tid) {
  __syncthreads();
  if (tid == 0) {
    unsigned prev = __hip_atomic_fetch_add(&B[0], 1u, __ATOMIC_RELAXED, AGS);
    if (prev == (unsigned)(NBLK - 1)) {
      __hip_atomic_store(&B[16], 1u, __ATOMIC_RELAXED, AGS);
    } else {
      while (__hip_atomic_load(&B[16], __ATOMIC_RELAXED, AGS) == 0u)
        __builtin_amdgcn_s_sleep(8);
    }
  }
  __syncthreads();
}

// Main: relaxed barrier; fast path relies on same-XCD L2 visibility (stores are
// in L2 at vmcnt0; consumer L1 provably cold for ping-pong buffer). If ANY block
// is not on its intended XCD (mybad), all blocks take the coherent fallback:
// threadfence (wbl2) -> barrier -> threadfence (inv).
__device__ __forceinline__ void gsyncx(unsigned int* B, int tid, int mybad,
                                       int* sbad) {
  __syncthreads();
  if (tid == 0) {
    if (mybad) {
      unsigned v = __hip_atomic_fetch_add(&B[32], 1u, __ATOMIC_RELAXED, AGS);
      if (v == 0xFFFFFFFFu)   // consume v: forces completion before count add
        __hip_atomic_store(&B[33], 1u, __ATOMIC_RELAXED, AGS);
    }
    unsigned prev = __hip_atomic_fetch_add(&B[0], 1u, __ATOMIC_RELAXED, AGS);
    unsigned g;
    if (prev == (unsigned)(NBLK - 1)) {
      unsigned ab = __hip_atomic_load(&B[32], __ATOMIC_RELAXED, AGS);
      g = 2u | (ab ? 1u : 0u);
      __hip_atomic_store(&B[16], g, __ATOMIC_RELAXED, AGS);
    } else {
      while ((g = __hip_atomic_load(&B[16], __ATOMIC_RELAXED, AGS)) == 0u)
        __builtin_amdgcn_s_sleep(8);
    }
    *sbad = (int)(g & 1u);
  }
  __syncthreads();
  if (*sbad) {          // coherent fallback (mapping violated): full flush
    __threadfence();
    gsync_plain(B + 64, tid);
    __threadfence();
  }
}

// ---------------- prep: weights -> fp16 fragment-linear tiles (one dispatch) ----------
__global__ __launch_bounds__(256) void k_prep(
    const float* __restrict__ W1, const float* __restrict__ W2,
    const float* __restrict__ Wqkv, const float* __restrict__ Wo,
    const float* __restrict__ Wcomb,
    _Float16* __restrict__ w1f, _Float16* __restrict__ w2f,
    _Float16* __restrict__ wqkvf, _Float16* __restrict__ wof,
    _Float16* __restrict__ wcombt, unsigned int* __restrict__ bar)
{
  __shared__ float t[64 * 65];
  int bx = blockIdx.x;
  int cc = threadIdx.x & 63, rr = threadIdx.x >> 6;

  if (bx == 0) bar[threadIdx.x] = 0;   // zero all 256 barrier words each launch

  if (bx >= 272) {  // Wcomb [80][64] -> wcombt [64][80]
    int r0 = (bx - 272) * 64;
#pragma unroll
    for (int i = 0; i < 16; i++) {
      int r = i * 4 + rr;
      if (r0 + r < 80) t[r * 65 + cc] = Wcomb[(size_t)(r0 + r) * 64 + cc];
    }
    __syncthreads();
#pragma unroll
    for (int i = 0; i < 16; i++) {
      int c = i * 4 + rr;
      if (r0 + c < 80) wcombt[(size_t)cc * 80 + r0 + c] = (_Float16)t[c * 65 + cc];
    }
    return;
  }

  const float* src; _Float16* dst; int astr;
  if (bx < 128) {        // W1 [64 k][2048 hid]: tile g = hid block
    int l = bx >> 5, g = bx & 31;
    src = W1 + (size_t)l * PERL + g * 64; astr = 2048;
    dst = w1f + (size_t)(l * 32 + g) * 4096;
  } else if (bx < 256) { // W2 [2048 k][64 n]: tile g = k block
    int j = bx - 128; int l = j >> 5, g = j & 31;
    src = W2 + (size_t)l * PERL + (size_t)g * 64 * 64; astr = 64;
    dst = w2f + (size_t)(l * 32 + g) * 4096;
  } else if (bx < 268) { // Wqkv [64 k][192 n]: 3 tiles per layer
    int j = bx - 256; int l = j / 3, g = j % 3;
    src = Wqkv + (size_t)l * 64 * 192 + g * 64; astr = 192;
    dst = wqkvf + (size_t)(l * 3 + g) * 4096;
  } else {               // Wo [64 k][64 n]
    int l = bx - 268;
    src = Wo + (size_t)l * 4096; astr = 64;
    dst = wof + (size_t)l * 4096;
  }
#pragma unroll
  for (int i = 0; i < 16; i++) {
    int a = i * 4 + rr;
    t[cc * 65 + a] = src[(size_t)a * astr + cc];  // t[m][k] = S[k][m]
  }
  __syncthreads();
#pragma unroll
  for (int it = 0; it < 2; it++) {
    int c = threadIdx.x + it * 256;
    int frag = c >> 6, lane = c & 63;
    int m = (frag >> 1) * 16 + (lane & 15);
    int k0 = (frag & 1) * 32 + (lane >> 4) * 8;
    const float* tr = &t[m * 65 + k0];
    half8 h;
#pragma unroll
    for (int j = 0; j < 8; j++) h[j] = (_Float16)tr[j];
    *(half8*)&dst[(size_t)c * 8] = h;
  }
}

// ---- QKV GEMM body (64-row blocks, 4 waves m2xn2) for embqkv; head-major stores ----
__device__ __forceinline__ void qkv_nb(
    const half8 (&af)[2][2], const _Float16* __restrict__ wqkvf,
    const float* __restrict__ bqkv, _Float16* __restrict__ qbuf,
    _Float16* __restrict__ kbuf, _Float16* __restrict__ vbuf,
    int bx, int nb, int wm, int wn, int lane)
{
  int quad = lane >> 4, l15 = lane & 15;
  const _Float16* bt = wqkvf + (size_t)nb * 4096;
  half8 bf[2][2];
#pragma unroll
  for (int nt = 0; nt < 2; nt++)
#pragma unroll
    for (int ks = 0; ks < 2; ks++)
      bf[nt][ks] = *(const half8*)&bt[(size_t)(((wn * 2 + nt) * 2 + ks) * 512) +
                                      lane * 8];
  f32x4 acc[2][2];
#pragma unroll
  for (int mt = 0; mt < 2; mt++)
#pragma unroll
    for (int nt = 0; nt < 2; nt++) {
      float bv = bqkv[nb * 64 + wn * 32 + nt * 16 + l15];
      acc[mt][nt] = (f32x4){bv, bv, bv, bv};
    }
#pragma unroll
  for (int ks = 0; ks < 2; ks++)
#pragma unroll
    for (int mt = 0; mt < 2; mt++)
#pragma unroll
      for (int nt = 0; nt < 2; nt++)
        acc[mt][nt] = __builtin_amdgcn_mfma_f32_16x16x32_f16(
            af[mt][ks], bf[nt][ks], acc[mt][nt], 0, 0, 0);
  _Float16* dst = (nb == 0) ? qbuf : ((nb == 1) ? kbuf : vbuf);
#pragma unroll
  for (int mt = 0; mt < 2; mt++)
#pragma unroll
    for (int nt = 0; nt < 2; nt++) {
      int col = wn * 32 + nt * 16 + l15;
      int h = col >> 3, d = col & 7;
#pragma unroll
      for (int r = 0; r < 4; r++) {
        int row = bx * 64 + wm * 32 + mt * 16 + quad * 4 + r;
        int b = row >> 10, rb = row & 1023;
        dst[((size_t)(b * 8 + h) * 1024 + rb) * 8 + d] = (_Float16)acc[mt][nt][r];
      }
    }
}

// ---- FFN helpers for 32-row blocks (2 waves per group; wn = wave-in-group) ----
__device__ __forceinline__ void ffn_load2(
    const _Float16* __restrict__ w1f, const _Float16* __restrict__ w2f, int g,
    half8 (&a1)[2][2], half8 (&b2w)[2][2], int wn, int lane)
{
  const _Float16* w1t_ = w1f + (size_t)g * 4096;
  const _Float16* w2t_ = w2f + (size_t)g * 4096;
#pragma unroll
  for (int ht = 0; ht < 2; ht++)
#pragma unroll
    for (int ks = 0; ks < 2; ks++)
      a1[ht][ks] = *(const half8*)&w1t_[(size_t)(((wn * 2 + ht) * 2 + ks) * 512) +
                                        lane * 8];
#pragma unroll
  for (int nt = 0; nt < 2; nt++)
#pragma unroll
    for (int ks = 0; ks < 2; ks++)
      b2w[nt][ks] = *(const half8*)&w2t_[(size_t)(((wn * 2 + nt) * 2 + ks) * 512) +
                                         lane * 8];
}

__device__ __forceinline__ void ffn_step2(
    const half8 (&a1)[2][2], const half8 (&b2w)[2][2], const half8 (&xb)[2][2],
    _Float16* hsbuf, const float* __restrict__ b1, int g, f32x4 (&acc)[2][2],
    int wn, int lane)
{
  int quad = lane >> 4, l15 = lane & 15;
  f32x4 hacc[2][2];
#pragma unroll
  for (int ht = 0; ht < 2; ht++)
#pragma unroll
    for (int mt = 0; mt < 2; mt++) hacc[ht][mt] = (f32x4){0.f, 0.f, 0.f, 0.f};
#pragma unroll
  for (int ks = 0; ks < 2; ks++)
#pragma unroll
    for (int ht = 0; ht < 2; ht++)
#pragma unroll
      for (int mt = 0; mt < 2; mt++)
        hacc[ht][mt] = __builtin_amdgcn_mfma_f32_16x16x32_f16(
            a1[ht][ks], xb[mt][ks], hacc[ht][mt], 0, 0, 0);
#pragma unroll
  for (int ht = 0; ht < 2; ht++) {
    float4 bb = *(const float4*)&b1[g * 64 + wn * 32 + ht * 16 + quad * 4];
#pragma unroll
    for (int mt = 0; mt < 2; mt++) {
      f32x4 hv = hacc[ht][mt];
      half4v hp = (half4v){
          (_Float16)fmaxf(hv[0] + bb.x, 0.f), (_Float16)fmaxf(hv[1] + bb.y, 0.f),
          (_Float16)fmaxf(hv[2] + bb.z, 0.f), (_Float16)fmaxf(hv[3] + bb.w, 0.f)};
      *(half4v*)&hsbuf[SW64(mt * 16 + l15, wn * 32 + ht * 16 + quad * 4)] = hp;
    }
  }
  __syncthreads();
#pragma unroll
  for (int ks = 0; ks < 2; ks++)
#pragma unroll
    for (int mt = 0; mt < 2; mt++) {
      half8 a2 = *(const half8*)&hsbuf[SW64(mt * 16 + l15, ks * 32 + quad * 8)];
#pragma unroll
      for (int nt = 0; nt < 2; nt++)
        acc[mt][nt] = __builtin_amdgcn_mfma_f32_16x16x32_f16(a2, b2w[nt][ks],
                                                             acc[mt][nt], 0, 0, 0);
    }
}

// ------- fused embed + comb GEMM + pos/type + QKV(layer0): writes x1, zm, q/k/v -------
__global__ __launch_bounds__(256) void k_embqkv(
    const float* __restrict__ features, const int* __restrict__ ovtag,
    const int* __restrict__ poiid, const float* __restrict__ W_raw,
    const float* __restrict__ b_raw, const float* __restrict__ ov_tab,
    const float* __restrict__ poi_tab, const _Float16* __restrict__ wcombt,
    const float* __restrict__ b_comb, const float* __restrict__ pos_tab,
    const float* __restrict__ type_tab, float* __restrict__ x1,
    float* __restrict__ zm, const _Float16* __restrict__ wqkvf,
    const float* __restrict__ bqkv, _Float16* __restrict__ qbuf,
    _Float16* __restrict__ kbuf, _Float16* __restrict__ vbuf)
{
  constexpr int KP = 104;
  __shared__ _Float16 As[64 * KP];
  __shared__ _Float16 Bs[64 * KP];
  __shared__ _Float16 xs[4096];
  int tid = threadIdx.x;
  int raw = blockIdx.x;
  int bx = ((raw & 7) << 5) + (raw >> 3);   // bijective on 256
  int m0 = bx * 64;
  int wave = tid >> 6, lane = tid & 63, quad = lane >> 4, l15 = lane & 15;
  int wm = wave >> 1, wn = wave & 1;
  for (int p = tid; p < 1536; p += 256) {
    int r = p / 24, s = p - r * 24; int c = s * 4;
    int row = m0 + r;
    float f0 = features[row * 3 + 0];
    float f1 = features[row * 3 + 1];
    float f2 = features[row * 3 + 2];
    if (s == 0) zm[row] = ((f0 + f1 + f2) == 0.f) ? 1.f : 0.f;
    half4v h;
#pragma unroll
    for (int j = 0; j < 4; j++) {
      int cc = c + j; float v;
      if (cc < 64) {
        v = b_raw[cc] + f0 * W_raw[cc] + f1 * W_raw[64 + cc] + f2 * W_raw[128 + cc];
      } else if (cc < 72) {
        int tt = ovtag[row]; v = (tt <= 0) ? 0.f : ov_tab[tt * 8 + cc - 64];
      } else if (cc < 80) {
        int tt = poiid[row]; v = (tt <= 0) ? 0.f : poi_tab[tt * 8 + cc - 72];
      } else v = 0.f;
      h[j] = (_Float16)v;
    }
    *(half4v*)&As[r * KP + c] = h;
  }
  for (int p = tid; p < 1536; p += 256) {
    int r = p / 24, s = p - r * 24; int c = s * 4;
    half4v h = (half4v){0, 0, 0, 0};
    if (c < 80) h = *(const half4v*)&wcombt[r * 80 + c];
    *(half4v*)&Bs[r * KP + c] = h;
  }
  __syncthreads();
  f32x4 acc[2][2];
#pragma unroll
  for (int mt = 0; mt < 2; mt++)
#pragma unroll
    for (int nt = 0; nt < 2; nt++) {
      float bv = b_comb[wn * 32 + nt * 16 + l15];
      acc[mt][nt] = (f32x4){bv, bv, bv, bv};
    }
#pragma unroll
  for (int ks = 0; ks < 3; ks++) {
    half8 af[2], bf[2];
#pragma unroll
    for (int mt = 0; mt < 2; mt++)
      af[mt] = *(const half8*)&As[(wm * 32 + mt * 16 + l15) * KP + ks * 32 + quad * 8];
#pragma unroll
    for (int nt = 0; nt < 2; nt++)
      bf[nt] = *(const half8*)&Bs[(wn * 32 + nt * 16 + l15) * KP + ks * 32 + quad * 8];
#pragma unroll
    for (int mt = 0; mt < 2; mt++)
#pragma unroll
      for (int nt = 0; nt < 2; nt++)
        acc[mt][nt] = __builtin_amdgcn_mfma_f32_16x16x32_f16(af[mt], bf[nt],
                                                             acc[mt][nt], 0, 0, 0);
  }
#pragma unroll
  for (int mt = 0; mt < 2; mt++)
#pragma unroll
    for (int nt = 0; nt < 2; nt++)
#pragma unroll
      for (int r = 0; r < 4; r++) {
        int lrow = wm * 32 + mt * 16 + quad * 4 + r;
        int row = m0 + lrow;
        int col = wn * 32 + nt * 16 + l15;
        int l = row & (LL - 1);
        float v = acc[mt][nt][r] +
            pos_tab[(l >> 6) * 64 + col] + type_tab[(l & 63) * 64 + col];
        x1[(size_t)row * 64 + col] = v;
        xs[SW64(lrow, col)] = (_Float16)v;
      }
  __syncthreads();
  half8 af[2][2];
#pragma unroll
  for (int mt = 0; mt < 2; mt++)
#pragma unroll
    for (int ks = 0; ks < 2; ks++)
      af[mt][ks] = *(const half8*)&xs[SW64(wm * 32 + mt * 16 + l15,
                                           ks * 32 + quad * 8)];
  for (int nb = 0; nb < 3; nb++)
    qkv_nb(af, wqkvf, bqkv, qbuf, kbuf, vbuf, bx, nb, wm, wn, lane);
}

// ---- fused 2-layer kernel: [attn+oproj+LN1+FFN+LN2+QKV] x2 with in-kernel
//      XCD-local barrier between halves. 512 blocks x 256 thr (2/CU exactly ->
//      all co-resident). x and q stay in LDS across the pair; only mid k/v
//      cross blocks (same-XCD under the batch->XCD swizzle; verified at runtime
//      via XCC_ID with a fully-coherent fallback). ----
__global__ __launch_bounds__(256, 2) void k_layer2(
    const _Float16* __restrict__ qin, const _Float16* __restrict__ kin,
    const _Float16* __restrict__ vin,
    _Float16* __restrict__ kM, _Float16* __restrict__ vM,
    _Float16* __restrict__ qout, _Float16* __restrict__ kout,
    _Float16* __restrict__ vout,
    const float* __restrict__ zm, float* __restrict__ x1,
    const _Float16* __restrict__ wofB, const float* __restrict__ boB,
    const float* __restrict__ ln1_sB, const float* __restrict__ ln1_bB,
    const _Float16* __restrict__ w1fB, const _Float16* __restrict__ w2fB,
    const float* __restrict__ b1B, const float* __restrict__ b2B,
    const float* __restrict__ ln2_sB, const float* __restrict__ ln2_bB,
    const _Float16* __restrict__ wqkvfB, const float* __restrict__ bqkvB,
    int l0, unsigned int* __restrict__ bar,
    const float* __restrict__ Wh, const float* __restrict__ bh,
    float* __restrict__ out)
{
  __shared__ float ots[32 * 68];                       // 8.7 KB
  __shared__ __align__(16) _Float16 xs[2048];          // 4 KB
  __shared__ float x2f[2048];                          // 8 KB (x, persists pair)
  __shared__ __align__(16) _Float16 hs[4][2048];       // 16 KB (FFN h / q-mid)
  __shared__ __align__(16) _Float16 os[2048];          // 4 KB (attn out)
  __shared__ float zsh[1024];                          // 4 KB (mask, persists)
  __shared__ __align__(16) _Float16 kvs[8192];         // 16 KB (uniform K/V)
  __shared__ int sbad;
  int tid = threadIdx.x;
  int raw = blockIdx.x;
  int bx = ((raw & 7) << 6) + (raw >> 3);   // bijective on 512; XCD = raw&7
  int r0 = bx * 32;
  int rb0 = r0 & 1023;
  int wave = tid >> 6, lane = tid & 63;
  int quad = lane >> 4, l15 = lane & 15;
  int grp = wave >> 1, wn = wave & 1;
  int b = r0 >> 10;
  int tq0 = rb0 >> 6;
  _Float16* qkvt = &hs[0][0];               // q of mid layer (alias; see timeline)

  int xcc = __builtin_amdgcn_s_getreg((31 << 11) | (0 << 6) | 20) & 15;
  int mybad = (xcc != (raw & 7)) ? 1 : 0;   // HW_REG_XCC_ID vs intended XCD

  for (int p = tid; p < 1024; p += 256)
    zsh[p] = (zm[b * LL + p] != 0.f) ? -20000.f : 0.f;

  for (int half = 0; half < 2; ++half) {
    const int l = l0 + half;
    const _Float16* wof_l = wofB + (size_t)l * 4096;
    const _Float16* w1l = w1fB + (size_t)l * PERL;
    const _Float16* w2l = w2fB + (size_t)l * PERL;
    const float* b1l = b1B + (size_t)l * DFF_;
    const _Float16* kb_base = half ? kM : kin;
    const _Float16* vb_base = half ? vM : vin;
    float ln1sv = ln1_sB[l * 64 + lane], ln1bv = ln1_bB[l * 64 + lane];
    float ln2sv = ln2_sB[l * 64 + lane], ln2bv = ln2_bB[l * 64 + lane];

    // stage uniform K/V window: rows [tq0*64, +64) for all 8 heads
    for (int p = tid; p < 512; p += 256) {
      int h = p >> 6, row = p & 63;
      size_t gidx = ((size_t)(b * 8 + h) * 1024 + tq0 * 64 + row) * 8;
      *(half8*)&kvs[h * 512 + row * 8] = *(const half8*)&kb_base[gidx];
      *(half8*)&kvs[4096 + h * 512 + row * 8] = *(const half8*)&vb_base[gidx];
    }
    // prefetch o-proj B frags + (half0) residual rows
    half8 obf[2][2];
#pragma unroll
    for (int nt = 0; nt < 2; nt++)
#pragma unroll
      for (int ks = 0; ks < 2; ks++)
        obf[nt][ks] = *(const half8*)&wof_l[(size_t)(((wn * 2 + nt) * 2 + ks) * 512)
                                            + lane * 8];
    float x1pre[8];
    if (half == 0) {
#pragma unroll
      for (int i = 0; i < 8; i++)
        x1pre[i] = x1[(size_t)(r0 + wave * 8 + i) * 64 + lane];
    }
    __syncthreads();

    // ---- attention ----
    {
      int lr = tid & 31, hh = tid >> 5;
      int rb = rb0 + lr;
      int vq = rb & 63;
      const _Float16* kb = kb_base + (size_t)(b * 8 + hh) * 8192;
      const _Float16* vb = vb_base + (size_t)(b * 8 + hh) * 8192;
      half8 qh;
      if (half == 0)
        qh = *(const half8*)&qin[(size_t)(b * 8 + hh) * 8192 + (size_t)rb * 8];
      else
        qh = *(const half8*)&qkvt[SW64(lr, hh * 8)];
      const float scale = 0.3535533905932738f;
      float m = -10000.f, lsum = 0.f;
      float acc[8] = {0.f, 0.f, 0.f, 0.f, 0.f, 0.f, 0.f, 0.f};
      bool zmq = (zsh[rb] < -1.f);

      auto dot = [&](half8 kk) -> float {
        float s = 0.f;
#ifdef HAVE_FDOT2
#pragma unroll
        for (int j = 0; j < 4; j++) {
          half2v qa = (half2v){qh[2 * j], qh[2 * j + 1]};
          half2v ka = (half2v){kk[2 * j], kk[2 * j + 1]};
          s = __builtin_amdgcn_fdot2(qa, ka, s, false);
        }
#else
#pragma unroll
        for (int j = 0; j < 8; j++) s += (float)qh[j] * (float)kk[j];
#endif
        return s;
      };
      auto update = [&](float s, half8 vv) {
        float nm = fmaxf(m, s);
        float r = __expf(m - nm);
        float p = __expf(s - nm);
        lsum = lsum * r + p;
#pragma unroll
        for (int d = 0; d < 8; d++) acc[d] = acc[d] * r + p * (float)vv[d];
        m = nm;
      };

      if (!zmq) {
        for (int base = 0; base < 64; base += 4) {
          half8 kk[4], vv[4]; float sv[4];
#pragma unroll
          for (int j = 0; j < 4; j++) {
            kk[j] = *(const half8*)&kvs[hh * 512 + (base + j) * 8];
            vv[j] = *(const half8*)&kvs[4096 + hh * 512 + (base + j) * 8];
          }
#pragma unroll
          for (int j = 0; j < 4; j++)
            sv[j] = dot(kk[j]) * scale + zsh[tq0 * 64 + base + j];
#pragma unroll
          for (int j = 0; j < 4; j++) update(sv[j], vv[j]);
        }
        for (int bb = 0; bb < 5; bb++) {
          half8 kk[3], vv[3]; float sv[3];
#pragma unroll
          for (int j = 0; j < 3; j++) {
            int cc = bb * 3 + j;
            int tt = cc + ((cc >= tq0) ? 1 : 0);
            int k = tt * 64 + vq;
            kk[j] = *(const half8*)&kb[(size_t)k * 8];
            vv[j] = *(const half8*)&vb[(size_t)k * 8];
            sv[j] = zsh[k];
          }
#pragma unroll
          for (int j = 0; j < 3; j++) sv[j] += dot(kk[j]) * scale;
#pragma unroll
          for (int j = 0; j < 3; j++) update(sv[j], vv[j]);
        }
      }
      float inv = (lsum > 0.f) ? 1.f / lsum : 0.f;
      half8 o;
#pragma unroll
      for (int d = 0; d < 8; d++) o[d] = (_Float16)(acc[d] * inv);
      *(half8*)&os[SW64(lr, hh * 8)] = o;
    }
    __syncthreads();

    // ---- o-proj ----
    {
      half8 af[2];
#pragma unroll
      for (int ks = 0; ks < 2; ks++)
        af[ks] = *(const half8*)&os[SW64(grp * 16 + l15, ks * 32 + quad * 8)];
      f32x4 acc[2];
#pragma unroll
      for (int nt = 0; nt < 2; nt++) {
        float bv = boB[l * 64 + wn * 32 + nt * 16 + l15];
        acc[nt] = (f32x4){bv, bv, bv, bv};
      }
#pragma unroll
      for (int ks = 0; ks < 2; ks++)
#pragma unroll
        for (int nt = 0; nt < 2; nt++)
          acc[nt] = __builtin_amdgcn_mfma_f32_16x16x32_f16(af[ks], obf[nt][ks],
                                                           acc[nt], 0, 0, 0);
#pragma unroll
      for (int nt = 0; nt < 2; nt++)
#pragma unroll
        for (int r = 0; r < 4; r++)
          ots[(grp * 16 + quad * 4 + r) * 68 + wn * 32 + nt * 16 + l15] =
              acc[nt][r];
    }
    half8 a1x[2][2], b2x[2][2], a1y[2][2], b2y[2][2];
    ffn_load2(w1l, w2l, grp, a1x, b2x, wn, lane);
    __syncthreads();
    // ---- residual + LN1 ----
    for (int i = 0; i < 8; i++) {
      int row = wave * 8 + i;
      float res = (half == 0) ? x1pre[i] : x2f[row * 64 + lane];
      float val = ots[row * 68 + lane] + res;
      float sum = val;
#pragma unroll
      for (int o = 32; o > 0; o >>= 1) sum += __shfl_xor(sum, o);
      float mean = sum * (1.f / 64.f);
      float d = val - mean;
      float sq = d * d;
#pragma unroll
      for (int o = 32; o > 0; o >>= 1) sq += __shfl_xor(sq, o);
      float xv = d * rsqrtf(sq * (1.f / 64.f) + 1e-5f) * ln1sv + ln1bv;
      x2f[row * 64 + lane] = xv;
      xs[SW64(row, lane)] = (_Float16)xv;
    }
    __syncthreads();

    // ---- FFN (2-stage pipelined, 16 chunk-steps per group) ----
    half8 xb[2][2];
#pragma unroll
    for (int mt = 0; mt < 2; mt++)
#pragma unroll
      for (int ks = 0; ks < 2; ks++)
        xb[mt][ks] = *(const half8*)&xs[SW64(mt * 16 + l15, ks * 32 + quad * 8)];
    f32x4 acc[2][2];
#pragma unroll
    for (int mt = 0; mt < 2; mt++)
#pragma unroll
      for (int nt = 0; nt < 2; nt++) {
        float bv = (grp == 0) ? b2B[l * 64 + wn * 32 + nt * 16 + l15] : 0.f;
        acc[mt][nt] = (f32x4){bv, bv, bv, bv};
      }
    for (int ii = 0; ii < 8; ii++) {
      ffn_load2(w1l, w2l, ii * 4 + 2 + grp, a1y, b2y, wn, lane);
      ffn_step2(a1x, b2x, xb, &hs[grp][0], b1l, ii * 4 + grp, acc, wn, lane);
      if (ii < 7) ffn_load2(w1l, w2l, ii * 4 + 4 + grp, a1x, b2x, wn, lane);
      ffn_step2(a1y, b2y, xb, &hs[grp + 2][0], b1l, ii * 4 + 2 + grp, acc, wn,
                lane);
    }
    __syncthreads();
    if (grp == 0) {
#pragma unroll
      for (int mt = 0; mt < 2; mt++)
#pragma unroll
        for (int nt = 0; nt < 2; nt++)
#pragma unroll
          for (int r = 0; r < 4; r++)
            ots[(mt * 16 + quad * 4 + r) * 68 + wn * 32 + nt * 16 + l15] =
                acc[mt][nt][r];
    }
    __syncthreads();
    if (grp == 1) {
#pragma unroll
      for (int mt = 0; mt < 2; mt++)
#pragma unroll
        for (int nt = 0; nt < 2; nt++)
#pragma unroll
          for (int r = 0; r < 4; r++)
            ots[(mt * 16 + quad * 4 + r) * 68 + wn * 32 + nt * 16 + l15] +=
                acc[mt][nt][r];
    }
    __syncthreads();
    // ---- residual + LN2 -> x2f (+ x1 only when crossing to next dispatch) ----
    for (int i = 0; i < 8; i++) {
      int row = wave * 8 + i;
      float val = ots[row * 68 + lane] + x2f[row * 64 + lane];
      float sum = val;
#pragma unroll
      for (int o = 32; o > 0; o >>= 1) sum += __shfl_xor(sum, o);
      float mean = sum * (1.f / 64.f);
      float d = val - mean;
      float sq = d * d;
#pragma unroll
      for (int o = 32; o > 0; o >>= 1) sq += __shfl_xor(sq, o);
      float xv = d * rsqrtf(sq * (1.f / 64.f) + 1e-5f) * ln2sv + ln2bv;
      if (half == 1 && l0 == 0)
        x1[(size_t)(r0 + row) * 64 + lane] = xv;
      x2f[row * 64 + lane] = xv;
      xs[SW64(row, lane)] = (_Float16)xv;
    }
    __syncthreads();

    if (l == 3) {
      // ---- head: blocks owning t==15 rows ----
      if ((bx & 31) >= 30 && tid < 96) {
        int bb2 = bx >> 5;
        int i = tid / 3, j = tid - i * 3;
        int vglob = (bx & 1) * 32 + i;
        float a = bh[j];
        for (int e = 0; e < 64; e++)
          a += x2f[i * 64 + e] * Wh[e * 3 + j];
        out[((size_t)(bb2 * 64 + vglob)) * 3 + j] = a;
      }
      return;
    }

    // ---- QKV for layer l+1 ----
    {
      const _Float16* wq = wqkvfB + (size_t)(l + 1) * 3 * 4096;
      const float* bq = bqkvB + (l + 1) * 192;
      half8 af[2][2];
#pragma unroll
      for (int mt = 0; mt < 2; mt++)
#pragma unroll
        for (int ks = 0; ks < 2; ks++)
          af[mt][ks] = *(const half8*)&xs[SW64(mt * 16 + l15, ks * 32 + quad * 8)];
      for (int nb = 0; nb < 3; nb++) {
        const _Float16* bt = wq + (size_t)nb * 4096;
        half8 bf[2];
#pragma unroll
        for (int ks = 0; ks < 2; ks++)
          bf[ks] = *(const half8*)&bt[(size_t)((wave * 2 + ks) * 512) + lane * 8];
        f32x4 qacc[2];
#pragma unroll
        for (int mt = 0; mt < 2; mt++) {
          float bv = bq[nb * 64 + wave * 16 + l15];
          qacc[mt] = (f32x4){bv, bv, bv, bv};
        }
#pragma unroll
        for (int ks = 0; ks < 2; ks++)
#pragma unroll
          for (int mt = 0; mt < 2; mt++)
            qacc[mt] = __builtin_amdgcn_mfma_f32_16x16x32_f16(af[mt][ks], bf[ks],
                                                              qacc[mt], 0, 0, 0);
        int col = wave * 16 + l15;
        int h2 = col >> 3, d2 = col & 7;
        if (half == 0) {
          if (nb == 0) {
            // q of mid layer -> LDS (consumed by this block's next attention)
#pragma unroll
            for (int mt = 0; mt < 2; mt++)
#pragma unroll
              for (int r = 0; r < 4; r++)
                qkvt[SW64(mt * 16 + quad * 4 + r, col)] = (_Float16)qacc[mt][r];
          } else {
            _Float16* dst = (nb == 1) ? kM : vM;
#pragma unroll
            for (int mt = 0; mt < 2; mt++)
#pragma unroll
              for (int r = 0; r < 4; r++) {
                int rbq = (r0 + mt * 16 + quad * 4 + r) & 1023;
                dst[((size_t)(b * 8 + h2) * 1024 + rbq) * 8 + d2] =
                    (_Float16)qacc[mt][r];
              }
          }
        } else {
          _Float16* dst = (nb == 0) ? qout : ((nb == 1) ? kout : vout);
#pragma unroll
          for (int mt = 0; mt < 2; mt++)
#pragma unroll
            for (int r = 0; r < 4; r++) {
              int rbq = (r0 + mt * 16 + quad * 4 + r) & 1023;
              dst[((size_t)(b * 8 + h2) * 1024 + rbq) * 8 + d2] =
                  (_Float16)qacc[mt][r];
            }
        }
      }
    }
    if (half == 0) gsyncx(bar, tid, mybad, &sbad);
  }
}

extern "C" void kernel_launch(void* const* d_in, const int* in_sizes, int n_in,
                              void* d_out, int out_size, void* d_ws, size_t ws_size,
                              hipStream_t stream) {
  const float* features = (const float*)d_in[0];
  const int*   ovtag    = (const int*)d_in[1];
  const int*   poiid    = (const int*)d_in[2];
  const float* W_raw    = (const float*)d_in[3];
  const float* b_raw    = (const float*)d_in[4];
  const float* pos_tab  = (const float*)d_in[5];
  const float* type_tab = (const float*)d_in[6];
  const float* poi_tab  = (const float*)d_in[7];
  const float* ov_tab   = (const float*)d_in[8];
  const float* W_comb   = (const float*)d_in[9];
  const float* b_comb   = (const float*)d_in[10];
  const float* Wqkv     = (const float*)d_in[11];
  const float* bqkv     = (const float*)d_in[12];
  const float* Wo       = (const float*)d_in[13];
  const float* bo       = (const float*)d_in[14];
  const float* ln1_s    = (const float*)d_in[15];
  const float* ln1_b    = (const float*)d_in[16];
  const float* W1       = (const float*)d_in[17];
  const float* b1       = (const float*)d_in[18];
  const float* W2       = (const float*)d_in[19];
  const float* b2       = (const float*)d_in[20];
  const float* ln2_s    = (const float*)d_in[21];
  const float* ln2_b    = (const float*)d_in[22];
  const float* W_head   = (const float*)d_in[23];
  const float* b_head   = (const float*)d_in[24];
  float* out = (float*)d_out;
  float* ws  = (float*)d_ws;

  float* zm  = ws;                              // BL
  float* x1  = zm + BL;                         // BL*64
  _Float16* qbA = (_Float16*)(x1 + (size_t)BL * 64);          // BL*64 (head-major)
  _Float16* kbA = qbA + (size_t)BL * 64;
  _Float16* vbA = kbA + (size_t)BL * 64;
  _Float16* qbB = vbA + (size_t)BL * 64;
  _Float16* kbB = qbB + (size_t)BL * 64;
  _Float16* vbB = kbB + (size_t)BL * 64;
  _Float16* kM  = vbB + (size_t)BL * 64;                      // mid-layer k
  _Float16* vM  = kM  + (size_t)BL * 64;                      // mid-layer v
  _Float16* wcombt = vM + (size_t)BL * 64;                    // 64*80
  _Float16* w1f    = wcombt + 5120;                           // NL*PERL
  _Float16* w2f    = w1f + (size_t)NLAYER * PERL;             // NL*PERL
  _Float16* wqkvf  = w2f + (size_t)NLAYER * PERL;             // NL*3*4096
  _Float16* wof    = wqkvf + (size_t)NLAYER * 3 * 4096;       // NL*4096
  unsigned int* bar = (unsigned int*)(wof + (size_t)NLAYER * 4096);  // 256 uints

  k_prep<<<274, 256, 0, stream>>>(W1, W2, Wqkv, Wo, W_comb,
                                  w1f, w2f, wqkvf, wof, wcombt, bar);
  k_embqkv<<<256, 256, 0, stream>>>(features, ovtag, poiid, W_raw, b_raw,
                                    ov_tab, poi_tab, wcombt, b_comb,
                                    pos_tab, type_tab, x1, zm,
                                    wqkvf, bqkv, qbA, kbA, vbA);
  k_layer2<<<NBLK, 256, 0, stream>>>(
      qbA, kbA, vbA, kM, vM, qbB, kbB, vbB, zm, x1,
      wof, bo, ln1_s, ln1_b, w1f, w2f, b1, b2, ln2_s, ln2_b,
      wqkvf, bqkv, 0, bar, W_head, b_head, out);
  k_layer2<<<NBLK, 256, 0, stream>>>(
      qbB, kbB, vbB, kM, vM, qbA, kbA, vbA, zm, x1,
      wof, bo, ln1_s, ln1_b, w1f, w2f, b1, b2, ln2_s, ln2_b,
      wqkvf, bqkv, 2, bar + 128, W_head, b_head, out);
}

// Round 13
// 273.514 us; speedup vs baseline: 1.3028x; 1.3028x over previous
//
#include <hip/hip_runtime.h>
#include <math.h>

#define BB 16
#define SS 16
#define VVV 64
#define EE 64
#define HHH 8
#define NLAYER 4
#define DFF_ 2048
#define LL 1024   /* S*V */
#define BL 16384  /* B*L */
#define PERL 131072  /* 64*2048 elems per layer of W1 (and W2); 32 tiles*4096 */

typedef __attribute__((ext_vector_type(8))) _Float16 half8;
typedef __attribute__((ext_vector_type(4))) _Float16 half4v;
typedef __attribute__((ext_vector_type(2))) _Float16 half2v;
typedef __attribute__((ext_vector_type(4))) float f32x4;

#if defined(__has_builtin)
#if __has_builtin(__builtin_amdgcn_fdot2)
#define HAVE_FDOT2 1
#endif
#endif

// XOR-swizzled index into row-major fp16 LDS tiles with 64-half (128 B) rows.
#define SW64(m, k)  (((m) << 6) + ((((k) >> 3) ^ ((m) & 7)) << 3) + ((k) & 7))

// Fragment-linear tile layout (64x64 fp16 = 8 frags of 512 halves):
//   A[m][k] -> frag = (m>>4)*2 + (k>>5); lane = ((k>>3)&3)*16 + (m&15); +(k&7)

// ---- FFN helpers for 32-row blocks (2 waves per group; wn = wave-in-group) ----
__device__ __forceinline__ void ffn_load2(
    const _Float16* __restrict__ w1f, const _Float16* __restrict__ w2f, int g,
    half8 (&a1)[2][2], half8 (&b2w)[2][2], int wn, int lane)
{
  const _Float16* w1t_ = w1f + (size_t)g * 4096;
  const _Float16* w2t_ = w2f + (size_t)g * 4096;
#pragma unroll
  for (int ht = 0; ht < 2; ht++)
#pragma unroll
    for (int ks = 0; ks < 2; ks++)
      a1[ht][ks] = *(const half8*)&w1t_[(size_t)(((wn * 2 + ht) * 2 + ks) * 512) +
                                        lane * 8];
#pragma unroll
  for (int nt = 0; nt < 2; nt++)
#pragma unroll
    for (int ks = 0; ks < 2; ks++)
      b2w[nt][ks] = *(const half8*)&w2t_[(size_t)(((wn * 2 + nt) * 2 + ks) * 512) +
                                         lane * 8];
}

__device__ __forceinline__ void ffn_step2(
    const half8 (&a1)[2][2], const half8 (&b2w)[2][2], const half8 (&xb)[2][2],
    _Float16* hsbuf, const float* __restrict__ b1, int g, f32x4 (&acc)[2][2],
    int wn, int lane)
{
  int quad = lane >> 4, l15 = lane & 15;
  f32x4 hacc[2][2];
#pragma unroll
  for (int ht = 0; ht < 2; ht++)
#pragma unroll
    for (int mt = 0; mt < 2; mt++) hacc[ht][mt] = (f32x4){0.f, 0.f, 0.f, 0.f};
#pragma unroll
  for (int ks = 0; ks < 2; ks++)
#pragma unroll
    for (int ht = 0; ht < 2; ht++)
#pragma unroll
      for (int mt = 0; mt < 2; mt++)
        hacc[ht][mt] = __builtin_amdgcn_mfma_f32_16x16x32_f16(
            a1[ht][ks], xb[mt][ks], hacc[ht][mt], 0, 0, 0);
#pragma unroll
  for (int ht = 0; ht < 2; ht++) {
    float4 bb = *(const float4*)&b1[g * 64 + wn * 32 + ht * 16 + quad * 4];
#pragma unroll
    for (int mt = 0; mt < 2; mt++) {
      f32x4 hv = hacc[ht][mt];
      half4v hp = (half4v){
          (_Float16)fmaxf(hv[0] + bb.x, 0.f), (_Float16)fmaxf(hv[1] + bb.y, 0.f),
          (_Float16)fmaxf(hv[2] + bb.z, 0.f), (_Float16)fmaxf(hv[3] + bb.w, 0.f)};
      *(half4v*)&hsbuf[SW64(mt * 16 + l15, wn * 32 + ht * 16 + quad * 4)] = hp;
    }
  }
  __syncthreads();
#pragma unroll
  for (int ks = 0; ks < 2; ks++)
#pragma unroll
    for (int mt = 0; mt < 2; mt++) {
      half8 a2 = *(const half8*)&hsbuf[SW64(mt * 16 + l15, ks * 32 + quad * 8)];
#pragma unroll
      for (int nt = 0; nt < 2; nt++)
        acc[mt][nt] = __builtin_amdgcn_mfma_f32_16x16x32_f16(a2, b2w[nt][ks],
                                                             acc[mt][nt], 0, 0, 0);
    }
}

// ------- merged prep + embed dispatch -------
// Blocks 0..271: weight prep (fp16 fragment-linear tiles).
// Blocks 272..527: embed role (raw-layout W_comb/Wqkv reads -> no prep dependency):
//   comb GEMM + pos/type -> x1 (fp16), zm, layer-0 q/k/v.
__global__ __launch_bounds__(256) void k_prepemb(
    const float* __restrict__ W1, const float* __restrict__ W2,
    const float* __restrict__ Wqkv, const float* __restrict__ Wo,
    const float* __restrict__ Wcomb,
    _Float16* __restrict__ w1f, _Float16* __restrict__ w2f,
    _Float16* __restrict__ wqkvf, _Float16* __restrict__ wof,
    const float* __restrict__ features, const int* __restrict__ ovtag,
    const int* __restrict__ poiid, const float* __restrict__ W_raw,
    const float* __restrict__ b_raw, const float* __restrict__ ov_tab,
    const float* __restrict__ poi_tab, const float* __restrict__ b_comb,
    const float* __restrict__ pos_tab, const float* __restrict__ type_tab,
    _Float16* __restrict__ x1h, float* __restrict__ zm,
    const float* __restrict__ bqkv, _Float16* __restrict__ qbuf,
    _Float16* __restrict__ kbuf, _Float16* __restrict__ vbuf)
{
  int gbx = blockIdx.x;
  int tid = threadIdx.x;

  if (gbx < 272) {
    // ---------------- prep role ----------------
    __shared__ float t[64 * 65];
    int bx = gbx;
    int cc = tid & 63, rr = tid >> 6;
    const float* src; _Float16* dst; int astr;
    if (bx < 128) {        // W1 [64 k][2048 hid]: tile g = hid block
      int l = bx >> 5, g = bx & 31;
      src = W1 + (size_t)l * PERL + g * 64; astr = 2048;
      dst = w1f + (size_t)(l * 32 + g) * 4096;
    } else if (bx < 256) { // W2 [2048 k][64 n]: tile g = k block
      int j = bx - 128; int l = j >> 5, g = j & 31;
      src = W2 + (size_t)l * PERL + (size_t)g * 64 * 64; astr = 64;
      dst = w2f + (size_t)(l * 32 + g) * 4096;
    } else if (bx < 268) { // Wqkv [64 k][192 n]: 3 tiles per layer
      int j = bx - 256; int l = j / 3, g = j % 3;
      src = Wqkv + (size_t)l * 64 * 192 + g * 64; astr = 192;
      dst = wqkvf + (size_t)(l * 3 + g) * 4096;
    } else {               // Wo [64 k][64 n]
      int l = bx - 268;
      src = Wo + (size_t)l * 4096; astr = 64;
      dst = wof + (size_t)l * 4096;
    }
#pragma unroll
    for (int i = 0; i < 16; i++) {
      int a = i * 4 + rr;
      t[cc * 65 + a] = src[(size_t)a * astr + cc];  // t[m][k] = S[k][m]
    }
    __syncthreads();
#pragma unroll
    for (int it = 0; it < 2; it++) {
      int c = tid + it * 256;
      int frag = c >> 6, lane = c & 63;
      int m = (frag >> 1) * 16 + (lane & 15);
      int k0 = (frag & 1) * 32 + (lane >> 4) * 8;
      const float* tr = &t[m * 65 + k0];
      half8 h;
#pragma unroll
      for (int j = 0; j < 8; j++) h[j] = (_Float16)tr[j];
      *(half8*)&dst[(size_t)c * 8] = h;
    }
    return;
  }

  // ---------------- embed role ----------------
  constexpr int KP = 104;
  __shared__ _Float16 As[64 * KP];
  __shared__ _Float16 Bs[64 * KP];
  __shared__ _Float16 xs[4096];
  int raw = gbx - 272;                       // 272 % 8 == 0: raw&7 == gbx&7 (XCD)
  int bx = ((raw & 7) << 5) + (raw >> 3);    // bijective on 256
  int m0 = bx * 64;
  int wave = tid >> 6, lane = tid & 63, quad = lane >> 4, l15 = lane & 15;
  int wm = wave >> 1, wn = wave & 1;
  for (int p = tid; p < 1536; p += 256) {
    int r = p / 24, s = p - r * 24; int c = s * 4;
    int row = m0 + r;
    float f0 = features[row * 3 + 0];
    float f1 = features[row * 3 + 1];
    float f2 = features[row * 3 + 2];
    if (s == 0) zm[row] = ((f0 + f1 + f2) == 0.f) ? 1.f : 0.f;
    half4v h;
#pragma unroll
    for (int j = 0; j < 4; j++) {
      int cc = c + j; float v;
      if (cc < 64) {
        v = b_raw[cc] + f0 * W_raw[cc] + f1 * W_raw[64 + cc] + f2 * W_raw[128 + cc];
      } else if (cc < 72) {
        int tt = ovtag[row]; v = (tt <= 0) ? 0.f : ov_tab[tt * 8 + cc - 64];
      } else if (cc < 80) {
        int tt = poiid[row]; v = (tt <= 0) ? 0.f : poi_tab[tt * 8 + cc - 72];
      } else v = 0.f;
      h[j] = (_Float16)v;
    }
    *(half4v*)&As[r * KP + c] = h;
  }
  // Bs[n][k] = W_comb[k][n], raw strided loads (20 KB table, L2-resident)
  for (int p = tid; p < 1536; p += 256) {
    int r = p / 24, s = p - r * 24; int c = s * 4;
    half4v h = (half4v){0, 0, 0, 0};
#pragma unroll
    for (int j = 0; j < 4; j++)
      if (c + j < 80) h[j] = (_Float16)Wcomb[(size_t)(c + j) * 64 + r];
    *(half4v*)&Bs[r * KP + c] = h;
  }
  __syncthreads();
  f32x4 acc[2][2];
#pragma unroll
  for (int mt = 0; mt < 2; mt++)
#pragma unroll
    for (int nt = 0; nt < 2; nt++) {
      float bv = b_comb[wn * 32 + nt * 16 + l15];
      acc[mt][nt] = (f32x4){bv, bv, bv, bv};
    }
#pragma unroll
  for (int ks = 0; ks < 3; ks++) {
    half8 af[2], bf[2];
#pragma unroll
    for (int mt = 0; mt < 2; mt++)
      af[mt] = *(const half8*)&As[(wm * 32 + mt * 16 + l15) * KP + ks * 32 + quad * 8];
#pragma unroll
    for (int nt = 0; nt < 2; nt++)
      bf[nt] = *(const half8*)&Bs[(wn * 32 + nt * 16 + l15) * KP + ks * 32 + quad * 8];
#pragma unroll
    for (int mt = 0; mt < 2; mt++)
#pragma unroll
      for (int nt = 0; nt < 2; nt++)
        acc[mt][nt] = __builtin_amdgcn_mfma_f32_16x16x32_f16(af[mt], bf[nt],
                                                             acc[mt][nt], 0, 0, 0);
  }
#pragma unroll
  for (int mt = 0; mt < 2; mt++)
#pragma unroll
    for (int nt = 0; nt < 2; nt++)
#pragma unroll
      for (int r = 0; r < 4; r++) {
        int lrow = wm * 32 + mt * 16 + quad * 4 + r;
        int row = m0 + lrow;
        int col = wn * 32 + nt * 16 + l15;
        int l = row & (LL - 1);
        float v = acc[mt][nt][r] +
            pos_tab[(l >> 6) * 64 + col] + type_tab[(l & 63) * 64 + col];
        x1h[(size_t)row * 64 + col] = (_Float16)v;
        xs[SW64(lrow, col)] = (_Float16)v;
      }
  __syncthreads();
  half8 af[2][2];
#pragma unroll
  for (int mt = 0; mt < 2; mt++)
#pragma unroll
    for (int ks = 0; ks < 2; ks++)
      af[mt][ks] = *(const half8*)&xs[SW64(wm * 32 + mt * 16 + l15,
                                           ks * 32 + quad * 8)];
  // layer-0 QKV with RAW Wqkv loads (no prep dependency); head-major stores
#pragma unroll
  for (int nb = 0; nb < 3; nb++) {
    half8 bf[2][2];
#pragma unroll
    for (int nt = 0; nt < 2; nt++)
#pragma unroll
      for (int ks = 0; ks < 2; ks++) {
        int n = nb * 64 + (wn * 2 + nt) * 16 + l15;
#pragma unroll
        for (int j = 0; j < 8; j++)
          bf[nt][ks][j] =
              (_Float16)Wqkv[(size_t)(ks * 32 + quad * 8 + j) * 192 + n];
      }
    f32x4 qacc[2][2];
#pragma unroll
    for (int mt = 0; mt < 2; mt++)
#pragma unroll
      for (int nt = 0; nt < 2; nt++) {
        float bv = bqkv[nb * 64 + wn * 32 + nt * 16 + l15];
        qacc[mt][nt] = (f32x4){bv, bv, bv, bv};
      }
#pragma unroll
    for (int ks = 0; ks < 2; ks++)
#pragma unroll
      for (int mt = 0; mt < 2; mt++)
#pragma unroll
        for (int nt = 0; nt < 2; nt++)
          qacc[mt][nt] = __builtin_amdgcn_mfma_f32_16x16x32_f16(
              af[mt][ks], bf[nt][ks], qacc[mt][nt], 0, 0, 0);
    _Float16* dst = (nb == 0) ? qbuf : ((nb == 1) ? kbuf : vbuf);
#pragma unroll
    for (int mt = 0; mt < 2; mt++)
#pragma unroll
      for (int nt = 0; nt < 2; nt++) {
        int col = wn * 32 + nt * 16 + l15;
        int h = col >> 3, d = col & 7;
#pragma unroll
        for (int r = 0; r < 4; r++) {
          int row = m0 + wm * 32 + mt * 16 + quad * 4 + r;
          int b = row >> 10, rb = row & 1023;
          dst[((size_t)(b * 8 + h) * 1024 + rb) * 8 + d] = (_Float16)qacc[mt][nt][r];
        }
      }
  }
}

// ---- fused layer kernel: attn + o-proj + LN1 + FFN + LN2 + (QKV_next | head) ----
// 512 blocks x 256 thr, 32 rows/block (2/CU, no spill). Attention: uniform K/V
// window staged in LDS; batched loads. x1 residual in fp16. First FFN weight
// pair loaded before attention (latency hidden). XCD-affinity swizzle.
__global__ __launch_bounds__(256, 2) void k_layerf(
    const _Float16* __restrict__ qin, const _Float16* __restrict__ kin,
    const _Float16* __restrict__ vin, const float* __restrict__ zm,
    const _Float16* __restrict__ wof, const float* __restrict__ bo,
    _Float16* __restrict__ x1h,
    const float* __restrict__ ln1_s, const float* __restrict__ ln1_b,
    const _Float16* __restrict__ w1f, const _Float16* __restrict__ w2f,
    const float* __restrict__ b1, const float* __restrict__ b2,
    const float* __restrict__ ln2_s, const float* __restrict__ ln2_b,
    const _Float16* __restrict__ wqkvf, const float* __restrict__ bqkv,
    _Float16* __restrict__ qout, _Float16* __restrict__ kout,
    _Float16* __restrict__ vout, int doqkv,
    const float* __restrict__ Wh, const float* __restrict__ bh,
    float* __restrict__ out)
{
  __shared__ float ots[32 * 68];                       // 8.7 KB
  __shared__ __align__(16) _Float16 xs[2048];          // 4 KB  (post-LN fp16, 32x64)
  __shared__ float x2f[2048];                          // 8 KB  (fp32 residual)
  __shared__ __align__(16) _Float16 hs[4][2048];       // 16 KB (FFN h tiles)
  __shared__ __align__(16) _Float16 os[2048];          // 4 KB  (attn out, SW64)
  __shared__ float zsh[1024];                          // 4 KB  (additive mask)
  __shared__ __align__(16) _Float16 kvs[8192];         // 16 KB (uniform K/V tile)
  __shared__ float ots2[32 * 68];                      // 8.7 KB
  int tid = threadIdx.x;
  int raw = blockIdx.x;
  int bx = ((raw & 7) << 6) + (raw >> 3);   // bijective on 512
  int r0 = bx * 32;
  int rb0 = r0 & 1023;
  int wave = tid >> 6, lane = tid & 63;
  int quad = lane >> 4, l15 = lane & 15;
  int grp = wave >> 1, wn = wave & 1;
  int b = r0 >> 10;                       // batch (blocks never cross b)
  int tq0 = rb0 >> 6;                     // block-uniform t-index

  for (int p = tid; p < 1024; p += 256)
    zsh[p] = (zm[b * LL + p] != 0.f) ? -20000.f : 0.f;
  // stage uniform K/V window: rows [tq0*64, tq0*64+64) for all 8 heads
  for (int p = tid; p < 512; p += 256) {
    int h = p >> 6, row = p & 63;
    size_t gidx = ((size_t)(b * 8 + h) * 1024 + tq0 * 64 + row) * 8;
    *(half8*)&kvs[h * 512 + row * 8] = *(const half8*)&kin[gidx];
    *(half8*)&kvs[4096 + h * 512 + row * 8] = *(const half8*)&vin[gidx];
  }

  // prefetch o-proj B frags + LN1 residual rows + LN params + FIRST FFN pair
  half8 obf[2][2];
#pragma unroll
  for (int nt = 0; nt < 2; nt++)
#pragma unroll
    for (int ks = 0; ks < 2; ks++)
      obf[nt][ks] = *(const half8*)&wof[(size_t)(((wn * 2 + nt) * 2 + ks) * 512) +
                                        lane * 8];
  float x1pre[8];
#pragma unroll
  for (int i = 0; i < 8; i++)
    x1pre[i] = (float)x1h[(size_t)(r0 + wave * 8 + i) * 64 + lane];
  float ln1sv = ln1_s[lane], ln1bv = ln1_b[lane];
  float ln2sv = ln2_s[lane], ln2bv = ln2_b[lane];
  half8 a1x[2][2], b2x[2][2], a1y[2][2], b2y[2][2];
  ffn_load2(w1f, w2f, grp, a1x, b2x, wn, lane);   // hidden under attention
  __syncthreads();

  // ---- attention: one (row, head) per thread; LDS uniform + batched scatter ----
  {
    int lr = tid & 31, hh = tid >> 5;
    int rb = rb0 + lr;
    int vq = rb & 63;
    const _Float16* kb = kin + (size_t)(b * 8 + hh) * 8192;
    const _Float16* vb = vin + (size_t)(b * 8 + hh) * 8192;
    half8 qh = *(const half8*)&qin[(size_t)(b * 8 + hh) * 8192 + (size_t)rb * 8];
    const float scale = 0.3535533905932738f;
    float m = -10000.f, lsum = 0.f;
    float acc[8] = {0.f, 0.f, 0.f, 0.f, 0.f, 0.f, 0.f, 0.f};
    bool zmq = (zsh[rb] < -1.f);

    auto dot = [&](half8 kk) -> float {
      float s = 0.f;
#ifdef HAVE_FDOT2
#pragma unroll
      for (int j = 0; j < 4; j++) {
        half2v qa = (half2v){qh[2 * j], qh[2 * j + 1]};
        half2v ka = (half2v){kk[2 * j], kk[2 * j + 1]};
        s = __builtin_amdgcn_fdot2(qa, ka, s, false);
      }
#else
#pragma unroll
      for (int j = 0; j < 8; j++) s += (float)qh[j] * (float)kk[j];
#endif
      return s;
    };
    auto update = [&](float s, half8 vv) {
      float nm = fmaxf(m, s);
      float r = __expf(m - nm);
      float p = __expf(s - nm);
      lsum = lsum * r + p;
#pragma unroll
      for (int d = 0; d < 8; d++) acc[d] = acc[d] * r + p * (float)vv[d];
      m = nm;
    };

    if (!zmq) {
      // uniform 64 keys from LDS (same-address broadcast per half-wave)
      for (int base = 0; base < 64; base += 4) {
        half8 kk[4], vv[4]; float sv[4];
#pragma unroll
        for (int j = 0; j < 4; j++) {
          kk[j] = *(const half8*)&kvs[hh * 512 + (base + j) * 8];
          vv[j] = *(const half8*)&kvs[4096 + hh * 512 + (base + j) * 8];
        }
#pragma unroll
        for (int j = 0; j < 4; j++)
          sv[j] = dot(kk[j]) * scale + zsh[tq0 * 64 + base + j];
#pragma unroll
        for (int j = 0; j < 4; j++) update(sv[j], vv[j]);
      }
      // 15 scattered keys (tt != tq0), 5 batches of 3; index = arith (no array)
      for (int bb = 0; bb < 5; bb++) {
        half8 kk[3], vv[3]; float sv[3];
#pragma unroll
        for (int j = 0; j < 3; j++) {
          int cc = bb * 3 + j;
          int tt = cc + ((cc >= tq0) ? 1 : 0);
          int k = tt * 64 + vq;
          kk[j] = *(const half8*)&kb[(size_t)k * 8];
          vv[j] = *(const half8*)&vb[(size_t)k * 8];
          sv[j] = zsh[k];
        }
#pragma unroll
        for (int j = 0; j < 3; j++) sv[j] += dot(kk[j]) * scale;
#pragma unroll
        for (int j = 0; j < 3; j++) update(sv[j], vv[j]);
      }
    }
    float inv = (lsum > 0.f) ? 1.f / lsum : 0.f;
    half8 o;
#pragma unroll
    for (int d = 0; d < 8; d++) o[d] = (_Float16)(acc[d] * inv);
    *(half8*)&os[SW64(lr, hh * 8)] = o;
  }
  __syncthreads();

  // ---- o-proj: wave covers m-tile (grp) x n-half (wn); A-frags from LDS os ----
  {
    half8 af[2];
#pragma unroll
    for (int ks = 0; ks < 2; ks++)
      af[ks] = *(const half8*)&os[SW64(grp * 16 + l15, ks * 32 + quad * 8)];
    f32x4 acc[2];
#pragma unroll
    for (int nt = 0; nt < 2; nt++) {
      float bv = bo[wn * 32 + nt * 16 + l15];
      acc[nt] = (f32x4){bv, bv, bv, bv};
    }
#pragma unroll
    for (int ks = 0; ks < 2; ks++)
#pragma unroll
      for (int nt = 0; nt < 2; nt++)
        acc[nt] = __builtin_amdgcn_mfma_f32_16x16x32_f16(af[ks], obf[nt][ks],
                                                         acc[nt], 0, 0, 0);
#pragma unroll
    for (int nt = 0; nt < 2; nt++)
#pragma unroll
      for (int r = 0; r < 4; r++)
        ots[(grp * 16 + quad * 4 + r) * 68 + wn * 32 + nt * 16 + l15] = acc[nt][r];
  }
  __syncthreads();
  // ---- residual + LN1 (4 waves x 8 rows) ----
  for (int i = 0; i < 8; i++) {
    int row = wave * 8 + i;
    float val = ots[row * 68 + lane] + x1pre[i];
    float sum = val;
#pragma unroll
    for (int o = 32; o > 0; o >>= 1) sum += __shfl_xor(sum, o);
    float mean = sum * (1.f / 64.f);
    float d = val - mean;
    float sq = d * d;
#pragma unroll
    for (int o = 32; o > 0; o >>= 1) sq += __shfl_xor(sq, o);
    float xv = d * rsqrtf(sq * (1.f / 64.f) + 1e-5f) * ln1sv + ln1bv;
    x2f[row * 64 + lane] = xv;
    xs[SW64(row, lane)] = (_Float16)xv;
  }
  __syncthreads();

  // ---- FFN: group g handles chunks 2i+g (16 chunks); explicit 2-stage pipeline ----
  half8 xb[2][2];
#pragma unroll
  for (int mt = 0; mt < 2; mt++)
#pragma unroll
    for (int ks = 0; ks < 2; ks++)
      xb[mt][ks] = *(const half8*)&xs[SW64(mt * 16 + l15, ks * 32 + quad * 8)];
  f32x4 acc[2][2];
#pragma unroll
  for (int mt = 0; mt < 2; mt++)
#pragma unroll
    for (int nt = 0; nt < 2; nt++) {
      float bv = (grp == 0) ? b2[wn * 32 + nt * 16 + l15] : 0.f;
      acc[mt][nt] = (f32x4){bv, bv, bv, bv};
    }
  for (int ii = 0; ii < 8; ii++) {
    ffn_load2(w1f, w2f, ii * 4 + 2 + grp, a1y, b2y, wn, lane);
    ffn_step2(a1x, b2x, xb, &hs[grp][0], b1, ii * 4 + grp, acc, wn, lane);
    if (ii < 7) ffn_load2(w1f, w2f, ii * 4 + 4 + grp, a1x, b2x, wn, lane);
    ffn_step2(a1y, b2y, xb, &hs[grp + 2][0], b1, ii * 4 + 2 + grp, acc, wn, lane);
  }
  // ---- cross-group reduce into ots ----
  __syncthreads();
  if (grp == 0) {
#pragma unroll
    for (int mt = 0; mt < 2; mt++)
#pragma unroll
      for (int nt = 0; nt < 2; nt++)
#pragma unroll
        for (int r = 0; r < 4; r++)
          ots[(mt * 16 + quad * 4 + r) * 68 + wn * 32 + nt * 16 + l15] =
              acc[mt][nt][r];
  }
  __syncthreads();
  if (grp == 1) {
#pragma unroll
    for (int mt = 0; mt < 2; mt++)
#pragma unroll
      for (int nt = 0; nt < 2; nt++)
#pragma unroll
        for (int r = 0; r < 4; r++)
          ots[(mt * 16 + quad * 4 + r) * 68 + wn * 32 + nt * 16 + l15] +=
              acc[mt][nt][r];
  }
  __syncthreads();
  // ---- residual + LN2 -> x1h (fp16, only if next layer exists) + xs + x2f ----
  for (int i = 0; i < 8; i++) {
    int row = wave * 8 + i;
    size_t off = (size_t)(r0 + row) * 64 + lane;
    float val = ots[row * 68 + lane] + x2f[row * 64 + lane];
    float sum = val;
#pragma unroll
    for (int o = 32; o > 0; o >>= 1) sum += __shfl_xor(sum, o);
    float mean = sum * (1.f / 64.f);
    float d = val - mean;
    float sq = d * d;
#pragma unroll
    for (int o = 32; o > 0; o >>= 1) sq += __shfl_xor(sq, o);
    float xv = d * rsqrtf(sq * (1.f / 64.f) + 1e-5f) * ln2sv + ln2bv;
    if (doqkv) x1h[off] = (_Float16)xv;
    x2f[row * 64 + lane] = xv;
    xs[SW64(row, lane)] = (_Float16)xv;
  }
  if (!doqkv) {
    // ---- fused head: blocks owning t==15 rows: bx%32 in {30,31} ----
    __syncthreads();
    if ((bx & 31) >= 30 && tid < 96) {
      int bb2 = bx >> 5;
      int i = tid / 3, j = tid - i * 3;
      int vglob = (bx & 1) * 32 + i;
      float a = bh[j];
      for (int e = 0; e < 64; e++)
        a += x2f[i * 64 + e] * Wh[e * 3 + j];
      out[((size_t)(bb2 * 64 + vglob)) * 3 + j] = a;
    }
    return;
  }
  __syncthreads();
  // ---- next layer's QKV: wave w covers n-16-tile w of each nb; m = 32 rows ----
  half8 af[2][2];
#pragma unroll
  for (int mt = 0; mt < 2; mt++)
#pragma unroll
    for (int ks = 0; ks < 2; ks++)
      af[mt][ks] = *(const half8*)&xs[SW64(mt * 16 + l15, ks * 32 + quad * 8)];
  for (int nb = 0; nb < 3; nb++) {
    const _Float16* bt = wqkvf + (size_t)nb * 4096;
    half8 bf[2];
#pragma unroll
    for (int ks = 0; ks < 2; ks++)
      bf[ks] = *(const half8*)&bt[(size_t)((wave * 2 + ks) * 512) + lane * 8];
    f32x4 qacc[2];
#pragma unroll
    for (int mt = 0; mt < 2; mt++) {
      float bv = bqkv[nb * 64 + wave * 16 + l15];
      qacc[mt] = (f32x4){bv, bv, bv, bv};
    }
#pragma unroll
    for (int ks = 0; ks < 2; ks++)
#pragma unroll
      for (int mt = 0; mt < 2; mt++)
        qacc[mt] = __builtin_amdgcn_mfma_f32_16x16x32_f16(af[mt][ks], bf[ks],
                                                          qacc[mt], 0, 0, 0);
    _Float16* dst = (nb == 0) ? qout : ((nb == 1) ? kout : vout);
    int col = wave * 16 + l15;
    int h2 = col >> 3, d2 = col & 7;
#pragma unroll
    for (int mt = 0; mt < 2; mt++)
#pragma unroll
      for (int r = 0; r < 4; r++) {
        int row = r0 + mt * 16 + quad * 4 + r;
        int rbq = row & 1023;
        dst[((size_t)(b * 8 + h2) * 1024 + rbq) * 8 + d2] = (_Float16)qacc[mt][r];
      }
  }
}

extern "C" void kernel_launch(void* const* d_in, const int* in_sizes, int n_in,
                              void* d_out, int out_size, void* d_ws, size_t ws_size,
                              hipStream_t stream) {
  const float* features = (const float*)d_in[0];
  const int*   ovtag    = (const int*)d_in[1];
  const int*   poiid    = (const int*)d_in[2];
  const float* W_raw    = (const float*)d_in[3];
  const float* b_raw    = (const float*)d_in[4];
  const float* pos_tab  = (const float*)d_in[5];
  const float* type_tab = (const float*)d_in[6];
  const float* poi_tab  = (const float*)d_in[7];
  const float* ov_tab   = (const float*)d_in[8];
  const float* W_comb   = (const float*)d_in[9];
  const float* b_comb   = (const float*)d_in[10];
  const float* Wqkv     = (const float*)d_in[11];
  const float* bqkv     = (const float*)d_in[12];
  const float* Wo       = (const float*)d_in[13];
  const float* bo       = (const float*)d_in[14];
  const float* ln1_s    = (const float*)d_in[15];
  const float* ln1_b    = (const float*)d_in[16];
  const float* W1       = (const float*)d_in[17];
  const float* b1       = (const float*)d_in[18];
  const float* W2       = (const float*)d_in[19];
  const float* b2       = (const float*)d_in[20];
  const float* ln2_s    = (const float*)d_in[21];
  const float* ln2_b    = (const float*)d_in[22];
  const float* W_head   = (const float*)d_in[23];
  const float* b_head   = (const float*)d_in[24];
  float* out = (float*)d_out;
  float* ws  = (float*)d_ws;

  float* zm  = ws;                              // BL
  _Float16* x1h = (_Float16*)(zm + BL);                       // BL*64 halves
  _Float16* qbA = x1h + (size_t)BL * 64;                      // BL*64 (head-major)
  _Float16* kbA = qbA + (size_t)BL * 64;
  _Float16* vbA = kbA + (size_t)BL * 64;
  _Float16* qbB = vbA + (size_t)BL * 64;                      // ping-pong gen B
  _Float16* kbB = qbB + (size_t)BL * 64;
  _Float16* vbB = kbB + (size_t)BL * 64;
  _Float16* w1f    = vbB + (size_t)BL * 64;                   // NL*PERL
  _Float16* w2f    = w1f + (size_t)NLAYER * PERL;             // NL*PERL
  _Float16* wqkvf  = w2f + (size_t)NLAYER * PERL;             // NL*3*4096
  _Float16* wof    = wqkvf + (size_t)NLAYER * 3 * 4096;       // NL*4096

  k_prepemb<<<528, 256, 0, stream>>>(W1, W2, Wqkv, Wo, W_comb,
                                     w1f, w2f, wqkvf, wof,
                                     features, ovtag, poiid, W_raw, b_raw,
                                     ov_tab, poi_tab, b_comb, pos_tab, type_tab,
                                     x1h, zm, bqkv, qbA, kbA, vbA);
  for (int l = 0; l < NLAYER; l++) {
    const _Float16* qin = (l & 1) ? qbB : qbA;
    const _Float16* kin = (l & 1) ? kbB : kbA;
    const _Float16* vin = (l & 1) ? vbB : vbA;
    _Float16* qout = (l & 1) ? qbA : qbB;
    _Float16* kout = (l & 1) ? kbA : kbB;
    _Float16* vout = (l & 1) ? vbA : vbB;
    int doqkv = (l < NLAYER - 1);
    k_layerf<<<512, 256, 0, stream>>>(
        qin, kin, vin, zm,
        wof + (size_t)l * 4096, bo + l * EE, x1h,
        ln1_s + l * EE, ln1_b + l * EE,
        w1f + (size_t)l * PERL, w2f + (size_t)l * PERL,
        b1 + l * DFF_, b2 + l * EE,
        ln2_s + l * EE, ln2_b + l * EE,
        wqkvf + (size_t)(l + 1 < NLAYER ? l + 1 : 0) * 3 * 4096,
        bqkv + (l + 1 < NLAYER ? l + 1 : 0) * 192,
        qout, kout, vout, doqkv, W_head, b_head, out);
  }
}

// Round 14
// 264.099 us; speedup vs baseline: 1.3492x; 1.0357x over previous
//
#include <hip/hip_runtime.h>
#include <math.h>

#define BB 16
#define SS 16
#define VVV 64
#define EE 64
#define HHH 8
#define NLAYER 4
#define DFF_ 2048
#define LL 1024   /* S*V */
#define BL 16384  /* B*L */
#define PERL 131072  /* 64*2048 elems per layer of W1 (and W2); 32 tiles*4096 */

typedef __attribute__((ext_vector_type(8))) _Float16 half8;
typedef __attribute__((ext_vector_type(4))) _Float16 half4v;
typedef __attribute__((ext_vector_type(2))) _Float16 half2v;
typedef __attribute__((ext_vector_type(4))) float f32x4;

#if defined(__has_builtin)
#if __has_builtin(__builtin_amdgcn_fdot2)
#define HAVE_FDOT2 1
#endif
#endif

// XOR-swizzled index into row-major fp16 LDS tiles with 64-half (128 B) rows.
#define SW64(m, k)  (((m) << 6) + ((((k) >> 3) ^ ((m) & 7)) << 3) + ((k) & 7))

// ---- FFN helpers (4 groups of 2 waves; wn = wave-in-group); 64-row tiles ----
__device__ __forceinline__ void ffn_load2(
    const _Float16* __restrict__ w1f, const _Float16* __restrict__ w2f, int g,
    half8 (&a1)[2][2], half8 (&b2w)[2][2], int wn, int lane)
{
  const _Float16* w1t_ = w1f + (size_t)g * 4096;
  const _Float16* w2t_ = w2f + (size_t)g * 4096;
#pragma unroll
  for (int ht = 0; ht < 2; ht++)
#pragma unroll
    for (int ks = 0; ks < 2; ks++)
      a1[ht][ks] = *(const half8*)&w1t_[(size_t)(((wn * 2 + ht) * 2 + ks) * 512) +
                                        lane * 8];
#pragma unroll
  for (int nt = 0; nt < 2; nt++)
#pragma unroll
    for (int ks = 0; ks < 2; ks++)
      b2w[nt][ks] = *(const half8*)&w2t_[(size_t)(((wn * 2 + nt) * 2 + ks) * 512) +
                                         lane * 8];
}

// one chunk over 64 rows (mt<4): gemm1 -> relu -> LDS h -> barrier -> gemm2
__device__ __forceinline__ void ffn_step4(
    const half8 (&a1)[2][2], const half8 (&b2w)[2][2], const half8 (&xb)[4][2],
    _Float16* hsbuf, const float* __restrict__ b1, int g, f32x4 (&acc)[4][2],
    int wn, int lane)
{
  int quad = lane >> 4, l15 = lane & 15;
#pragma unroll
  for (int ht = 0; ht < 2; ht++) {
    f32x4 hacc[4];
#pragma unroll
    for (int mt = 0; mt < 4; mt++) hacc[mt] = (f32x4){0.f, 0.f, 0.f, 0.f};
#pragma unroll
    for (int ks = 0; ks < 2; ks++)
#pragma unroll
      for (int mt = 0; mt < 4; mt++)
        hacc[mt] = __builtin_amdgcn_mfma_f32_16x16x32_f16(
            a1[ht][ks], xb[mt][ks], hacc[mt], 0, 0, 0);
    float4 bb = *(const float4*)&b1[g * 64 + wn * 32 + ht * 16 + quad * 4];
#pragma unroll
    for (int mt = 0; mt < 4; mt++) {
      f32x4 hv = hacc[mt];
      half4v hp = (half4v){
          (_Float16)fmaxf(hv[0] + bb.x, 0.f), (_Float16)fmaxf(hv[1] + bb.y, 0.f),
          (_Float16)fmaxf(hv[2] + bb.z, 0.f), (_Float16)fmaxf(hv[3] + bb.w, 0.f)};
      *(half4v*)&hsbuf[SW64(mt * 16 + l15, wn * 32 + ht * 16 + quad * 4)] = hp;
    }
  }
  __syncthreads();
#pragma unroll
  for (int ks = 0; ks < 2; ks++)
#pragma unroll
    for (int mt = 0; mt < 4; mt++) {
      half8 a2 = *(const half8*)&hsbuf[SW64(mt * 16 + l15, ks * 32 + quad * 8)];
#pragma unroll
      for (int nt = 0; nt < 2; nt++)
        acc[mt][nt] = __builtin_amdgcn_mfma_f32_16x16x32_f16(a2, b2w[nt][ks],
                                                             acc[mt][nt], 0, 0, 0);
    }
}

// ------- merged prep + embed dispatch -------
__global__ __launch_bounds__(256) void k_prepemb(
    const float* __restrict__ W1, const float* __restrict__ W2,
    const float* __restrict__ Wqkv, const float* __restrict__ Wo,
    const float* __restrict__ Wcomb,
    _Float16* __restrict__ w1f, _Float16* __restrict__ w2f,
    _Float16* __restrict__ wqkvf, _Float16* __restrict__ wof,
    const float* __restrict__ features, const int* __restrict__ ovtag,
    const int* __restrict__ poiid, const float* __restrict__ W_raw,
    const float* __restrict__ b_raw, const float* __restrict__ ov_tab,
    const float* __restrict__ poi_tab, const float* __restrict__ b_comb,
    const float* __restrict__ pos_tab, const float* __restrict__ type_tab,
    _Float16* __restrict__ x1h, float* __restrict__ zm,
    const float* __restrict__ bqkv, _Float16* __restrict__ qbuf,
    _Float16* __restrict__ kbuf, _Float16* __restrict__ vbuf)
{
  int gbx = blockIdx.x;
  int tid = threadIdx.x;

  if (gbx < 272) {
    // ---------------- prep role ----------------
    __shared__ float t[64 * 65];
    int bx = gbx;
    int cc = tid & 63, rr = tid >> 6;
    const float* src; _Float16* dst; int astr;
    if (bx < 128) {
      int l = bx >> 5, g = bx & 31;
      src = W1 + (size_t)l * PERL + g * 64; astr = 2048;
      dst = w1f + (size_t)(l * 32 + g) * 4096;
    } else if (bx < 256) {
      int j = bx - 128; int l = j >> 5, g = j & 31;
      src = W2 + (size_t)l * PERL + (size_t)g * 64 * 64; astr = 64;
      dst = w2f + (size_t)(l * 32 + g) * 4096;
    } else if (bx < 268) {
      int j = bx - 256; int l = j / 3, g = j % 3;
      src = Wqkv + (size_t)l * 64 * 192 + g * 64; astr = 192;
      dst = wqkvf + (size_t)(l * 3 + g) * 4096;
    } else {
      int l = bx - 268;
      src = Wo + (size_t)l * 4096; astr = 64;
      dst = wof + (size_t)l * 4096;
    }
#pragma unroll
    for (int i = 0; i < 16; i++) {
      int a = i * 4 + rr;
      t[cc * 65 + a] = src[(size_t)a * astr + cc];
    }
    __syncthreads();
#pragma unroll
    for (int it = 0; it < 2; it++) {
      int c = tid + it * 256;
      int frag = c >> 6, lane = c & 63;
      int m = (frag >> 1) * 16 + (lane & 15);
      int k0 = (frag & 1) * 32 + (lane >> 4) * 8;
      const float* tr = &t[m * 65 + k0];
      half8 h;
#pragma unroll
      for (int j = 0; j < 8; j++) h[j] = (_Float16)tr[j];
      *(half8*)&dst[(size_t)c * 8] = h;
    }
    return;
  }

  // ---------------- embed role ----------------
  constexpr int KP = 104;
  __shared__ _Float16 As[64 * KP];
  __shared__ _Float16 Bs[64 * KP];
  __shared__ _Float16 xs[4096];
  int raw = gbx - 272;
  int bx = ((raw & 7) << 5) + (raw >> 3);
  int m0 = bx * 64;
  int wave = tid >> 6, lane = tid & 63, quad = lane >> 4, l15 = lane & 15;
  int wm = wave >> 1, wn = wave & 1;
  for (int p = tid; p < 1536; p += 256) {
    int r = p / 24, s = p - r * 24; int c = s * 4;
    int row = m0 + r;
    float f0 = features[row * 3 + 0];
    float f1 = features[row * 3 + 1];
    float f2 = features[row * 3 + 2];
    if (s == 0) zm[row] = ((f0 + f1 + f2) == 0.f) ? 1.f : 0.f;
    half4v h;
#pragma unroll
    for (int j = 0; j < 4; j++) {
      int cc = c + j; float v;
      if (cc < 64) {
        v = b_raw[cc] + f0 * W_raw[cc] + f1 * W_raw[64 + cc] + f2 * W_raw[128 + cc];
      } else if (cc < 72) {
        int tt = ovtag[row]; v = (tt <= 0) ? 0.f : ov_tab[tt * 8 + cc - 64];
      } else if (cc < 80) {
        int tt = poiid[row]; v = (tt <= 0) ? 0.f : poi_tab[tt * 8 + cc - 72];
      } else v = 0.f;
      h[j] = (_Float16)v;
    }
    *(half4v*)&As[r * KP + c] = h;
  }
  for (int p = tid; p < 1536; p += 256) {
    int r = p / 24, s = p - r * 24; int c = s * 4;
    half4v h = (half4v){0, 0, 0, 0};
#pragma unroll
    for (int j = 0; j < 4; j++)
      if (c + j < 80) h[j] = (_Float16)Wcomb[(size_t)(c + j) * 64 + r];
    *(half4v*)&Bs[r * KP + c] = h;
  }
  __syncthreads();
  f32x4 acc[2][2];
#pragma unroll
  for (int mt = 0; mt < 2; mt++)
#pragma unroll
    for (int nt = 0; nt < 2; nt++) {
      float bv = b_comb[wn * 32 + nt * 16 + l15];
      acc[mt][nt] = (f32x4){bv, bv, bv, bv};
    }
#pragma unroll
  for (int ks = 0; ks < 3; ks++) {
    half8 af[2], bf[2];
#pragma unroll
    for (int mt = 0; mt < 2; mt++)
      af[mt] = *(const half8*)&As[(wm * 32 + mt * 16 + l15) * KP + ks * 32 + quad * 8];
#pragma unroll
    for (int nt = 0; nt < 2; nt++)
      bf[nt] = *(const half8*)&Bs[(wn * 32 + nt * 16 + l15) * KP + ks * 32 + quad * 8];
#pragma unroll
    for (int mt = 0; mt < 2; mt++)
#pragma unroll
      for (int nt = 0; nt < 2; nt++)
        acc[mt][nt] = __builtin_amdgcn_mfma_f32_16x16x32_f16(af[mt], bf[nt],
                                                             acc[mt][nt], 0, 0, 0);
  }
#pragma unroll
  for (int mt = 0; mt < 2; mt++)
#pragma unroll
    for (int nt = 0; nt < 2; nt++)
#pragma unroll
      for (int r = 0; r < 4; r++) {
        int lrow = wm * 32 + mt * 16 + quad * 4 + r;
        int row = m0 + lrow;
        int col = wn * 32 + nt * 16 + l15;
        int l = row & (LL - 1);
        float v = acc[mt][nt][r] +
            pos_tab[(l >> 6) * 64 + col] + type_tab[(l & 63) * 64 + col];
        x1h[(size_t)row * 64 + col] = (_Float16)v;
        xs[SW64(lrow, col)] = (_Float16)v;
      }
  __syncthreads();
  half8 af[2][2];
#pragma unroll
  for (int mt = 0; mt < 2; mt++)
#pragma unroll
    for (int ks = 0; ks < 2; ks++)
      af[mt][ks] = *(const half8*)&xs[SW64(wm * 32 + mt * 16 + l15,
                                           ks * 32 + quad * 8)];
#pragma unroll
  for (int nb = 0; nb < 3; nb++) {
    half8 bf[2][2];
#pragma unroll
    for (int nt = 0; nt < 2; nt++)
#pragma unroll
      for (int ks = 0; ks < 2; ks++) {
        int n = nb * 64 + (wn * 2 + nt) * 16 + l15;
#pragma unroll
        for (int j = 0; j < 8; j++)
          bf[nt][ks][j] =
              (_Float16)Wqkv[(size_t)(ks * 32 + quad * 8 + j) * 192 + n];
      }
    f32x4 qacc[2][2];
#pragma unroll
    for (int mt = 0; mt < 2; mt++)
#pragma unroll
      for (int nt = 0; nt < 2; nt++) {
        float bv = bqkv[nb * 64 + wn * 32 + nt * 16 + l15];
        qacc[mt][nt] = (f32x4){bv, bv, bv, bv};
      }
#pragma unroll
    for (int ks = 0; ks < 2; ks++)
#pragma unroll
      for (int mt = 0; mt < 2; mt++)
#pragma unroll
        for (int nt = 0; nt < 2; nt++)
          qacc[mt][nt] = __builtin_amdgcn_mfma_f32_16x16x32_f16(
              af[mt][ks], bf[nt][ks], qacc[mt][nt], 0, 0, 0);
    _Float16* dst = (nb == 0) ? qbuf : ((nb == 1) ? kbuf : vbuf);
#pragma unroll
    for (int mt = 0; mt < 2; mt++)
#pragma unroll
      for (int nt = 0; nt < 2; nt++) {
        int col = wn * 32 + nt * 16 + l15;
        int h = col >> 3, d = col & 7;
#pragma unroll
        for (int r = 0; r < 4; r++) {
          int row = m0 + wm * 32 + mt * 16 + quad * 4 + r;
          int b = row >> 10, rb = row & 1023;
          dst[((size_t)(b * 8 + h) * 1024 + rb) * 8 + d] = (_Float16)qacc[mt][nt][r];
        }
      }
  }
}

// ---- fused layer kernel, 64 rows/block x 512 thr (8 waves), 256 blocks (1/CU).
//      Each weight fragment feeds 64 rows -> FFN L2 weight traffic per CU halved.
//      attn: 1 thread per (row,head), block-own t-window in LDS (broadcast reads).
//      XCD-affinity: raw&7 = XCD; XCD x owns batches {2x, 2x+1}. LDS ~126 KB. ----
__global__ __launch_bounds__(512, 1) void k_layerf(
    const _Float16* __restrict__ qin, const _Float16* __restrict__ kin,
    const _Float16* __restrict__ vin, const float* __restrict__ zm,
    const _Float16* __restrict__ wof, const float* __restrict__ bo,
    _Float16* __restrict__ x1h,
    const float* __restrict__ ln1_s, const float* __restrict__ ln1_b,
    const _Float16* __restrict__ w1f, const _Float16* __restrict__ w2f,
    const float* __restrict__ b1, const float* __restrict__ b2,
    const float* __restrict__ ln2_s, const float* __restrict__ ln2_b,
    const _Float16* __restrict__ wqkvf, const float* __restrict__ bqkv,
    _Float16* __restrict__ qout, _Float16* __restrict__ kout,
    _Float16* __restrict__ vout, int doqkv,
    const float* __restrict__ Wh, const float* __restrict__ bh,
    float* __restrict__ out)
{
  __shared__ __align__(16) char smem[129024];
  float*    ots  = (float*)smem;                     // 17408 (64x68)
  float*    ots2 = (float*)(smem + 17408);           // 17408
  _Float16* xs   = (_Float16*)(smem + 34816);        // 8192  (64x64 fp16, SW64)
  float*    x2f  = (float*)(smem + 43008);           // 16384 (64x64 f32)
  _Float16* hs   = (_Float16*)(smem + 59392);        // 65536 (8 bufs x 64x64)
  float*    zsh  = (float*)(smem + 124928);          // 4096
  _Float16* os   = (_Float16*)(smem + 59392);        // alias hs buf0 (attn out)
  _Float16* kvs  = (_Float16*)(smem + 59392 + 8192); // alias hs buf1-2 (K/V tile)
  int tid = threadIdx.x;
  int raw = blockIdx.x;
  int bx = ((raw & 7) << 5) + (raw >> 3);   // bijective on 256; XCD = raw&7
  int r0 = bx * 64;
  int rb0 = r0 & 1023;
  int wave = tid >> 6, lane = tid & 63;
  int quad = lane >> 4, l15 = lane & 15;
  int grp = wave >> 1, wn = wave & 1;
  int b = r0 >> 10;
  int tq0 = bx & 15;                        // block == one t-group

  for (int p = tid; p < 1024; p += 512)
    zsh[p] = (zm[b * LL + p] != 0.f) ? -20000.f : 0.f;
  // stage block-own K/V window: rows [tq0*64, +64) x 8 heads (16 KB)
  {
    int h = tid >> 6, row = tid & 63;
    size_t gidx = ((size_t)(b * 8 + h) * 1024 + tq0 * 64 + row) * 8;
    *(half8*)&kvs[h * 512 + row * 8] = *(const half8*)&kin[gidx];
    *(half8*)&kvs[4096 + h * 512 + row * 8] = *(const half8*)&vin[gidx];
  }

  // prefetches (hidden under attention)
  half8 obf[2][2];
#pragma unroll
  for (int nt = 0; nt < 2; nt++)
#pragma unroll
    for (int ks = 0; ks < 2; ks++)
      obf[nt][ks] = *(const half8*)&wof[(size_t)(((wn * 2 + nt) * 2 + ks) * 512) +
                                        lane * 8];
  float x1pre[8];
#pragma unroll
  for (int i = 0; i < 8; i++)
    x1pre[i] = (float)x1h[(size_t)(r0 + wave * 8 + i) * 64 + lane];
  float ln1sv = ln1_s[lane], ln1bv = ln1_b[lane];
  float ln2sv = ln2_s[lane], ln2bv = ln2_b[lane];
  half8 a1x[2][2], b2x[2][2], a1y[2][2], b2y[2][2];
  ffn_load2(w1f, w2f, grp, a1x, b2x, wn, lane);
  __syncthreads();

  // ---- attention: thread = (row lr, head hh); wave-uniform head -> broadcast ----
  {
    int lr = tid & 63, hh = tid >> 6;
    int rb = rb0 + lr;
    const _Float16* kb = kin + (size_t)(b * 8 + hh) * 8192;
    const _Float16* vb = vin + (size_t)(b * 8 + hh) * 8192;
    half8 qh = *(const half8*)&qin[(size_t)(b * 8 + hh) * 8192 + (size_t)rb * 8];
    const float scale = 0.3535533905932738f;
    float m = -10000.f, lsum = 0.f;
    float acc[8] = {0.f, 0.f, 0.f, 0.f, 0.f, 0.f, 0.f, 0.f};
    bool zmq = (zsh[rb] < -1.f);

    auto dot = [&](half8 kk) -> float {
      float s = 0.f;
#ifdef HAVE_FDOT2
#pragma unroll
      for (int j = 0; j < 4; j++) {
        half2v qa = (half2v){qh[2 * j], qh[2 * j + 1]};
        half2v ka = (half2v){kk[2 * j], kk[2 * j + 1]};
        s = __builtin_amdgcn_fdot2(qa, ka, s, false);
      }
#else
#pragma unroll
      for (int j = 0; j < 8; j++) s += (float)qh[j] * (float)kk[j];
#endif
      return s;
    };
    auto update = [&](float s, half8 vv) {
      float nm = fmaxf(m, s);
      float r = __expf(m - nm);
      float p = __expf(s - nm);
      lsum = lsum * r + p;
#pragma unroll
      for (int d = 0; d < 8; d++) acc[d] = acc[d] * r + p * (float)vv[d];
      m = nm;
    };

    if (!zmq) {
      for (int base = 0; base < 64; base += 4) {
        half8 kk[4], vv[4]; float sv[4];
#pragma unroll
        for (int j = 0; j < 4; j++) {
          kk[j] = *(const half8*)&kvs[hh * 512 + (base + j) * 8];
          vv[j] = *(const half8*)&kvs[4096 + hh * 512 + (base + j) * 8];
        }
#pragma unroll
        for (int j = 0; j < 4; j++)
          sv[j] = dot(kk[j]) * scale + zsh[tq0 * 64 + base + j];
#pragma unroll
        for (int j = 0; j < 4; j++) update(sv[j], vv[j]);
      }
      for (int bb = 0; bb < 5; bb++) {
        half8 kk[3], vv[3]; float sv[3];
#pragma unroll
        for (int j = 0; j < 3; j++) {
          int cc = bb * 3 + j;
          int tt = cc + ((cc >= tq0) ? 1 : 0);
          int k = tt * 64 + lr;       // vq == lr (rb0 is 64-aligned)
          kk[j] = *(const half8*)&kb[(size_t)k * 8];
          vv[j] = *(const half8*)&vb[(size_t)k * 8];
          sv[j] = zsh[k];
        }
#pragma unroll
        for (int j = 0; j < 3; j++) sv[j] += dot(kk[j]) * scale;
#pragma unroll
        for (int j = 0; j < 3; j++) update(sv[j], vv[j]);
      }
    }
    float inv = (lsum > 0.f) ? 1.f / lsum : 0.f;
    half8 o;
#pragma unroll
    for (int d = 0; d < 8; d++) o[d] = (_Float16)(acc[d] * inv);
    *(half8*)&os[SW64(lr, hh * 8)] = o;
  }
  __syncthreads();

  // ---- o-proj: wave = m-16-tile (wave>>1) x n-half (wave&1) ----
  {
    int mt_g = wave >> 1;
    half8 af[2];
#pragma unroll
    for (int ks = 0; ks < 2; ks++)
      af[ks] = *(const half8*)&os[SW64(mt_g * 16 + l15, ks * 32 + quad * 8)];
    f32x4 acc[2];
#pragma unroll
    for (int nt = 0; nt < 2; nt++) {
      float bv = bo[wn * 32 + nt * 16 + l15];
      acc[nt] = (f32x4){bv, bv, bv, bv};
    }
#pragma unroll
    for (int ks = 0; ks < 2; ks++)
#pragma unroll
      for (int nt = 0; nt < 2; nt++)
        acc[nt] = __builtin_amdgcn_mfma_f32_16x16x32_f16(af[ks], obf[nt][ks],
                                                         acc[nt], 0, 0, 0);
#pragma unroll
    for (int nt = 0; nt < 2; nt++)
#pragma unroll
      for (int r = 0; r < 4; r++)
        ots[(mt_g * 16 + quad * 4 + r) * 68 + wn * 32 + nt * 16 + l15] = acc[nt][r];
  }
  __syncthreads();
  // ---- residual + LN1 (8 waves x 8 rows) ----
  for (int i = 0; i < 8; i++) {
    int row = wave * 8 + i;
    float val = ots[row * 68 + lane] + x1pre[i];
    float sum = val;
#pragma unroll
    for (int o = 32; o > 0; o >>= 1) sum += __shfl_xor(sum, o);
    float mean = sum * (1.f / 64.f);
    float d = val - mean;
    float sq = d * d;
#pragma unroll
    for (int o = 32; o > 0; o >>= 1) sq += __shfl_xor(sq, o);
    float xv = d * rsqrtf(sq * (1.f / 64.f) + 1e-5f) * ln1sv + ln1bv;
    x2f[row * 64 + lane] = xv;
    xs[SW64(row, lane)] = (_Float16)xv;
  }
  __syncthreads();

  // ---- FFN: group g (of 4) handles chunks {8i+g, 8i+4+g}, i<4; 2-stage pipe ----
  half8 xb[4][2];
#pragma unroll
  for (int mt = 0; mt < 4; mt++)
#pragma unroll
    for (int ks = 0; ks < 2; ks++)
      xb[mt][ks] = *(const half8*)&xs[SW64(mt * 16 + l15, ks * 32 + quad * 8)];
  f32x4 acc[4][2];
#pragma unroll
  for (int mt = 0; mt < 4; mt++)
#pragma unroll
    for (int nt = 0; nt < 2; nt++) {
      float bv = (grp == 0) ? b2[wn * 32 + nt * 16 + l15] : 0.f;
      acc[mt][nt] = (f32x4){bv, bv, bv, bv};
    }
  for (int ii = 0; ii < 4; ii++) {
    ffn_load2(w1f, w2f, ii * 8 + 4 + grp, a1y, b2y, wn, lane);
    ffn_step4(a1x, b2x, xb, &hs[(size_t)grp * 4096], b1, ii * 8 + grp, acc, wn,
              lane);
    if (ii < 3) ffn_load2(w1f, w2f, ii * 8 + 8 + grp, a1x, b2x, wn, lane);
    ffn_step4(a1y, b2y, xb, &hs[(size_t)(grp + 4) * 4096], b1, ii * 8 + 4 + grp,
              acc, wn, lane);
  }
  // ---- cross-group reduce: g0/g1 write ots/ots2; g2/g3 add ----
  __syncthreads();
  if (grp < 2) {
    float* dst = (grp == 0) ? ots : ots2;
#pragma unroll
    for (int mt = 0; mt < 4; mt++)
#pragma unroll
      for (int nt = 0; nt < 2; nt++)
#pragma unroll
        for (int r = 0; r < 4; r++)
          dst[(mt * 16 + quad * 4 + r) * 68 + wn * 32 + nt * 16 + l15] =
              acc[mt][nt][r];
  }
  __syncthreads();
  if (grp >= 2) {
    float* dst = (grp == 2) ? ots : ots2;
#pragma unroll
    for (int mt = 0; mt < 4; mt++)
#pragma unroll
      for (int nt = 0; nt < 2; nt++)
#pragma unroll
        for (int r = 0; r < 4; r++)
          dst[(mt * 16 + quad * 4 + r) * 68 + wn * 32 + nt * 16 + l15] +=
              acc[mt][nt][r];
  }
  __syncthreads();
  // ---- residual + LN2 -> x1h (if next layer) + xs + x2f ----
  for (int i = 0; i < 8; i++) {
    int row = wave * 8 + i;
    size_t off = (size_t)(r0 + row) * 64 + lane;
    float val = ots[row * 68 + lane] + ots2[row * 68 + lane] +
                x2f[row * 64 + lane];
    float sum = val;
#pragma unroll
    for (int o = 32; o > 0; o >>= 1) sum += __shfl_xor(sum, o);
    float mean = sum * (1.f / 64.f);
    float d = val - mean;
    float sq = d * d;
#pragma unroll
    for (int o = 32; o > 0; o >>= 1) sq += __shfl_xor(sq, o);
    float xv = d * rsqrtf(sq * (1.f / 64.f) + 1e-5f) * ln2sv + ln2bv;
    if (doqkv) x1h[off] = (_Float16)xv;
    x2f[row * 64 + lane] = xv;
    xs[SW64(row, lane)] = (_Float16)xv;
  }
  if (!doqkv) {
    // ---- fused head: blocks with t == 15 (bx & 15 == 15); one per batch ----
    __syncthreads();
    if ((bx & 15) == 15 && tid < 192) {
      int bb2 = bx >> 4;
      int i = tid / 3, j = tid - i * 3;
      float a = bh[j];
      for (int e = 0; e < 64; e++)
        a += x2f[i * 64 + e] * Wh[e * 3 + j];
      out[((size_t)(bb2 * 64 + i)) * 3 + j] = a;
    }
    return;
  }
  __syncthreads();
  // ---- next layer's QKV: wave = m-half (wave>>2) x n-16-tile (wave&3) ----
  {
    int mh = wave >> 2, ntile = wave & 3;
    half8 af[2][2];
#pragma unroll
    for (int mt = 0; mt < 2; mt++)
#pragma unroll
      for (int ks = 0; ks < 2; ks++)
        af[mt][ks] = *(const half8*)&xs[SW64(mh * 32 + mt * 16 + l15,
                                             ks * 32 + quad * 8)];
    for (int nb = 0; nb < 3; nb++) {
      const _Float16* bt = wqkvf + (size_t)nb * 4096;
      half8 bf[2];
#pragma unroll
      for (int ks = 0; ks < 2; ks++)
        bf[ks] = *(const half8*)&bt[(size_t)((ntile * 2 + ks) * 512) + lane * 8];
      f32x4 qacc[2];
#pragma unroll
      for (int mt = 0; mt < 2; mt++) {
        float bv = bqkv[nb * 64 + ntile * 16 + l15];
        qacc[mt] = (f32x4){bv, bv, bv, bv};
      }
#pragma unroll
      for (int ks = 0; ks < 2; ks++)
#pragma unroll
        for (int mt = 0; mt < 2; mt++)
          qacc[mt] = __builtin_amdgcn_mfma_f32_16x16x32_f16(af[mt][ks], bf[ks],
                                                            qacc[mt], 0, 0, 0);
      _Float16* dst = (nb == 0) ? qout : ((nb == 1) ? kout : vout);
      int col = ntile * 16 + l15;
      int h2 = col >> 3, d2 = col & 7;
#pragma unroll
      for (int mt = 0; mt < 2; mt++)
#pragma unroll
        for (int r = 0; r < 4; r++) {
          int row = r0 + mh * 32 + mt * 16 + quad * 4 + r;
          int rbq = row & 1023;
          dst[((size_t)(b * 8 + h2) * 1024 + rbq) * 8 + d2] = (_Float16)qacc[mt][r];
        }
    }
  }
}

extern "C" void kernel_launch(void* const* d_in, const int* in_sizes, int n_in,
                              void* d_out, int out_size, void* d_ws, size_t ws_size,
                              hipStream_t stream) {
  const float* features = (const float*)d_in[0];
  const int*   ovtag    = (const int*)d_in[1];
  const int*   poiid    = (const int*)d_in[2];
  const float* W_raw    = (const float*)d_in[3];
  const float* b_raw    = (const float*)d_in[4];
  const float* pos_tab  = (const float*)d_in[5];
  const float* type_tab = (const float*)d_in[6];
  const float* poi_tab  = (const float*)d_in[7];
  const float* ov_tab   = (const float*)d_in[8];
  const float* W_comb   = (const float*)d_in[9];
  const float* b_comb   = (const float*)d_in[10];
  const float* Wqkv     = (const float*)d_in[11];
  const float* bqkv     = (const float*)d_in[12];
  const float* Wo       = (const float*)d_in[13];
  const float* bo       = (const float*)d_in[14];
  const float* ln1_s    = (const float*)d_in[15];
  const float* ln1_b    = (const float*)d_in[16];
  const float* W1       = (const float*)d_in[17];
  const float* b1       = (const float*)d_in[18];
  const float* W2       = (const float*)d_in[19];
  const float* b2       = (const float*)d_in[20];
  const float* ln2_s    = (const float*)d_in[21];
  const float* ln2_b    = (const float*)d_in[22];
  const float* W_head   = (const float*)d_in[23];
  const float* b_head   = (const float*)d_in[24];
  float* out = (float*)d_out;
  float* ws  = (float*)d_ws;

  float* zm  = ws;                              // BL
  _Float16* x1h = (_Float16*)(zm + BL);                       // BL*64 halves
  _Float16* qbA = x1h + (size_t)BL * 64;                      // BL*64 (head-major)
  _Float16* kbA = qbA + (size_t)BL * 64;
  _Float16* vbA = kbA + (size_t)BL * 64;
  _Float16* qbB = vbA + (size_t)BL * 64;                      // ping-pong gen B
  _Float16* kbB = qbB + (size_t)BL * 64;
  _Float16* vbB = kbB + (size_t)BL * 64;
  _Float16* w1f    = vbB + (size_t)BL * 64;                   // NL*PERL
  _Float16* w2f    = w1f + (size_t)NLAYER * PERL;             // NL*PERL
  _Float16* wqkvf  = w2f + (size_t)NLAYER * PERL;             // NL*3*4096
  _Float16* wof    = wqkvf + (size_t)NLAYER * 3 * 4096;       // NL*4096

  k_prepemb<<<528, 256, 0, stream>>>(W1, W2, Wqkv, Wo, W_comb,
                                     w1f, w2f, wqkvf, wof,
                                     features, ovtag, poiid, W_raw, b_raw,
                                     ov_tab, poi_tab, b_comb, pos_tab, type_tab,
                                     x1h, zm, bqkv, qbA, kbA, vbA);
  for (int l = 0; l < NLAYER; l++) {
    const _Float16* qin = (l & 1) ? qbB : qbA;
    const _Float16* kin = (l & 1) ? kbB : kbA;
    const _Float16* vin = (l & 1) ? vbB : vbA;
    _Float16* qout = (l & 1) ? qbA : qbB;
    _Float16* kout = (l & 1) ? kbA : kbB;
    _Float16* vout = (l & 1) ? vbA : vbB;
    int doqkv = (l < NLAYER - 1);
    k_layerf<<<256, 512, 0, stream>>>(
        qin, kin, vin, zm,
        wof + (size_t)l * 4096, bo + l * EE, x1h,
        ln1_s + l * EE, ln1_b + l * EE,
        w1f + (size_t)l * PERL, w2f + (size_t)l * PERL,
        b1 + l * DFF_, b2 + l * EE,
        ln2_s + l * EE, ln2_b + l * EE,
        wqkvf + (size_t)(l + 1 < NLAYER ? l + 1 : 0) * 3 * 4096,
        bqkv + (l + 1 < NLAYER ? l + 1 : 0) * 192,
        qout, kout, vout, doqkv, W_head, b_head, out);
  }
}